// Round 1
// baseline (1667.721 us; speedup 1.0000x reference)
//
#include <hip/hip_runtime.h>

#define N_NODES 20000
#define E_EDGES 320000
#define EN_TOT  (E_EDGES + N_NODES)   // edges + self loops = 340000
#define IN_DIM  512
#define H1      2
#define C1      128
#define HC1     256                    // H1*C1
#define OUT_DIM 64

// ---------- helpers: monotone float<->uint for atomicMax ----------
__device__ __forceinline__ unsigned int fenc(float f) {
  unsigned int u = __float_as_uint(f);
  return (u & 0x80000000u) ? ~u : (u | 0x80000000u);
}
__device__ __forceinline__ float fdec(unsigned int k) {
  unsigned int u = (k & 0x80000000u) ? (k & 0x7FFFFFFFu) : ~k;
  return __uint_as_float(u);
}

// ---------- tiled fp32 GEMM: C[M,Ncol] = A[M,K] @ B[K,Ncol] + bias ----------
template<int BM, int BN, int BK>
__global__ void gemm_bias_kernel(const float* __restrict__ A, const float* __restrict__ B,
                                 const float* __restrict__ bias, float* __restrict__ C,
                                 int M, int K, int Ncol) {
  __shared__ __align__(16) float As[BK][BM + 1];
  __shared__ __align__(16) float Bs[BK][BN];
  const int bm = blockIdx.x * BM;
  const int bn = blockIdx.y * BN;
  const int tid = threadIdx.x;           // 256 threads
  const int tx = tid & 15, ty = tid >> 4;
  float acc[4][4] = {};
  for (int k0 = 0; k0 < K; k0 += BK) {
    // A tile: BM x BK, float4 per thread along K
    {
      int row = tid >> 2;
      int kk  = (tid & 3) * 4;
      int gr  = bm + row;
      float4 v = make_float4(0.f, 0.f, 0.f, 0.f);
      if (gr < M) v = *reinterpret_cast<const float4*>(A + (size_t)gr * K + k0 + kk);
      As[kk + 0][row] = v.x; As[kk + 1][row] = v.y;
      As[kk + 2][row] = v.z; As[kk + 3][row] = v.w;
    }
    // B tile: BK x BN, float4 per thread along N
    {
      int kr = tid >> 4;
      int cc = (tid & 15) * 4;
      float4 v = *reinterpret_cast<const float4*>(B + (size_t)(k0 + kr) * Ncol + bn + cc);
      *reinterpret_cast<float4*>(&Bs[kr][cc]) = v;
    }
    __syncthreads();
#pragma unroll
    for (int kc = 0; kc < BK; ++kc) {
      float a[4], b[4];
#pragma unroll
      for (int i = 0; i < 4; ++i) a[i] = As[kc][ty * 4 + i];
#pragma unroll
      for (int j = 0; j < 4; ++j) b[j] = Bs[kc][tx * 4 + j];
#pragma unroll
      for (int i = 0; i < 4; ++i)
#pragma unroll
        for (int j = 0; j < 4; ++j)
          acc[i][j] += a[i] * b[j];
    }
    __syncthreads();
  }
#pragma unroll
  for (int i = 0; i < 4; ++i) {
    int gr = bm + ty * 4 + i;
    if (gr >= M) continue;
#pragma unroll
    for (int j = 0; j < 4; ++j) {
      int gc = bn + tx * 4 + j;
      C[(size_t)gr * Ncol + gc] = acc[i][j] + bias[gc];
    }
  }
}

// ---------- self-loop attr: deg + attr sums ----------
__global__ void edge_stats_kernel(const int* __restrict__ dst, const float* __restrict__ eattr,
                                  float* __restrict__ deg, float* __restrict__ asum) {
  int e = blockIdx.x * blockDim.x + threadIdx.x;
  if (e >= E_EDGES) return;
  int d = dst[e];
  atomicAdd(&deg[d], 1.0f);
  atomicAdd(&asum[d], eattr[e]);
}

__global__ void loop_attr_kernel(const float* __restrict__ deg, const float* __restrict__ asum,
                                 float* __restrict__ la) {
  int n = blockIdx.x * blockDim.x + threadIdx.x;
  if (n >= N_NODES) return;
  la[n] = asum[n] / fmaxf(deg[n], 1.0f);
}

// ---------- layer 1 alpha: wave per edge, 256 channels, 2 heads ----------
__global__ void alpha1_kernel(const int* __restrict__ src, const int* __restrict__ dst,
                              const float* __restrict__ eattr, const float* __restrict__ la,
                              const float* __restrict__ xl, const float* __restrict__ xr,
                              const float* __restrict__ We, const float* __restrict__ att,
                              float* __restrict__ alpha, unsigned int* __restrict__ amax) {
  int wid = threadIdx.x >> 6, lane = threadIdx.x & 63;
  int e = blockIdx.x * 4 + wid;             // EN_TOT divisible by 4
  int s, d; float ea;
  if (e < E_EDGES) { s = src[e]; d = dst[e]; ea = eattr[e]; }
  else             { s = d = e - E_EDGES;   ea = la[s]; }
  int c4 = lane * 4;
  float4 vl = *reinterpret_cast<const float4*>(xl + (size_t)s * HC1 + c4);
  float4 vr = *reinterpret_cast<const float4*>(xr + (size_t)d * HC1 + c4);
  float4 ve = *reinterpret_cast<const float4*>(We + c4);
  float4 va = *reinterpret_cast<const float4*>(att + c4);
  float p = 0.f, m;
  m = vl.x + vr.x + ea * ve.x; m = m > 0.f ? m : 0.2f * m; p += m * va.x;
  m = vl.y + vr.y + ea * ve.y; m = m > 0.f ? m : 0.2f * m; p += m * va.y;
  m = vl.z + vr.z + ea * ve.z; m = m > 0.f ? m : 0.2f * m; p += m * va.z;
  m = vl.w + vr.w + ea * ve.w; m = m > 0.f ? m : 0.2f * m; p += m * va.w;
#pragma unroll
  for (int off = 1; off <= 16; off <<= 1) p += __shfl_xor(p, off, 64);
  if (lane == 0 || lane == 32) {
    int h = lane >> 5;
    alpha[(size_t)e * H1 + h] = p;
    atomicMax(&amax[(size_t)d * H1 + h], fenc(p));
  }
}

// ---------- exp + denom (generic H) ----------
__global__ void expdenom_kernel(const float* __restrict__ alpha, const unsigned int* __restrict__ amax,
                                const int* __restrict__ dst, float* __restrict__ ez,
                                float* __restrict__ denom, int H) {
  int idx = blockIdx.x * blockDim.x + threadIdx.x;
  if (idx >= EN_TOT * H) return;
  int e = idx / H, h = idx - e * H;
  int d = (e < E_EDGES) ? dst[e] : (e - E_EDGES);
  float z = expf(alpha[idx] - fdec(amax[d * H + h]));
  ez[idx] = z;
  atomicAdd(&denom[d * H + h], z);
}

// ---------- layer 1 scatter: out[d] += xl[s] * a ----------
__global__ void scatter1_kernel(const int* __restrict__ src, const int* __restrict__ dst,
                                const float* __restrict__ xl, const float* __restrict__ ez,
                                const float* __restrict__ denom, float* __restrict__ acc) {
  int wid = threadIdx.x >> 6, lane = threadIdx.x & 63;
  int e = blockIdx.x * 4 + wid;
  int s, d;
  if (e < E_EDGES) { s = src[e]; d = dst[e]; }
  else             { s = d = e - E_EDGES; }
  int h = lane >> 5;
  float a = ez[(size_t)e * H1 + h] / denom[(size_t)d * H1 + h];
  int c4 = lane * 4;
  float4 vl = *reinterpret_cast<const float4*>(xl + (size_t)s * HC1 + c4);
  float* dp = acc + (size_t)d * HC1 + c4;
  atomicAdd(dp + 0, vl.x * a);
  atomicAdd(dp + 1, vl.y * a);
  atomicAdd(dp + 2, vl.z * a);
  atomicAdd(dp + 3, vl.w * a);
}

// ---------- bias + elu (layer1 epilogue, in place) ----------
__global__ void bias_elu_kernel(float* __restrict__ h, const float* __restrict__ bias) {
  int idx = blockIdx.x * blockDim.x + threadIdx.x;
  if (idx >= N_NODES * HC1) return;
  float v = h[idx] + bias[idx & (HC1 - 1)];
  h[idx] = v > 0.f ? v : expm1f(v);
}

// ---------- layer 2 alpha: wave per edge, 64 channels, 1 head ----------
__global__ void alpha2_kernel(const int* __restrict__ src, const int* __restrict__ dst,
                              const float* __restrict__ eattr, const float* __restrict__ la,
                              const float* __restrict__ xl, const float* __restrict__ xr,
                              const float* __restrict__ We, const float* __restrict__ att,
                              float* __restrict__ alpha, unsigned int* __restrict__ amax) {
  int wid = threadIdx.x >> 6, lane = threadIdx.x & 63;
  int e = blockIdx.x * 4 + wid;
  int s, d; float ea;
  if (e < E_EDGES) { s = src[e]; d = dst[e]; ea = eattr[e]; }
  else             { s = d = e - E_EDGES;   ea = la[s]; }
  float m = xl[(size_t)s * OUT_DIM + lane] + xr[(size_t)d * OUT_DIM + lane] + ea * We[lane];
  m = m > 0.f ? m : 0.2f * m;
  float p = m * att[lane];
#pragma unroll
  for (int off = 1; off <= 32; off <<= 1) p += __shfl_xor(p, off, 64);
  if (lane == 0) {
    alpha[e] = p;
    atomicMax(&amax[d], fenc(p));
  }
}

// ---------- layer 2 scatter ----------
__global__ void scatter2_kernel(const int* __restrict__ src, const int* __restrict__ dst,
                                const float* __restrict__ xl, const float* __restrict__ ez,
                                const float* __restrict__ denom, float* __restrict__ out) {
  int wid = threadIdx.x >> 6, lane = threadIdx.x & 63;
  int e = blockIdx.x * 4 + wid;
  int s, d;
  if (e < E_EDGES) { s = src[e]; d = dst[e]; }
  else             { s = d = e - E_EDGES; }
  float a = ez[e] / denom[d];
  atomicAdd(out + (size_t)d * OUT_DIM + lane, xl[(size_t)s * OUT_DIM + lane] * a);
}

// ---------- final bias add ----------
__global__ void bias_add_kernel(float* __restrict__ out, const float* __restrict__ bias) {
  int idx = blockIdx.x * blockDim.x + threadIdx.x;
  if (idx >= N_NODES * OUT_DIM) return;
  out[idx] += bias[idx & (OUT_DIM - 1)];
}

extern "C" void kernel_launch(void* const* d_in, const int* in_sizes, int n_in,
                              void* d_out, int out_size, void* d_ws, size_t ws_size,
                              hipStream_t stream) {
  const float* x     = (const float*)d_in[0];
  const int*   ei    = (const int*)d_in[1];
  const float* eattr = (const float*)d_in[2];
  const float* W1l   = (const float*)d_in[3];
  const float* b1l   = (const float*)d_in[4];
  const float* W1r   = (const float*)d_in[5];
  const float* b1r   = (const float*)d_in[6];
  const float* W1e   = (const float*)d_in[7];
  const float* att1  = (const float*)d_in[8];
  const float* bias1 = (const float*)d_in[9];
  const float* W2l   = (const float*)d_in[10];
  const float* b2l   = (const float*)d_in[11];
  const float* W2r   = (const float*)d_in[12];
  const float* b2r   = (const float*)d_in[13];
  const float* W2e   = (const float*)d_in[14];
  const float* att2  = (const float*)d_in[15];
  const float* bias2 = (const float*)d_in[16];
  const int* src = ei;
  const int* dst = ei + E_EDGES;
  float* out = (float*)d_out;

  // workspace layout (floats)
  float* ws    = (float*)d_ws;
  float* xl1   = ws;                       // N*HC1 = 5,120,000
  float* xr1   = xl1 + (size_t)N_NODES * HC1;
  float* hacc  = xr1 + (size_t)N_NODES * HC1;   // layer1 accum -> h after elu
  float* xl2   = hacc + (size_t)N_NODES * HC1;  // N*64
  float* xr2   = xl2 + (size_t)N_NODES * OUT_DIM;
  float* alpha1= xr2 + (size_t)N_NODES * OUT_DIM;  // EN*2
  float* ez1   = alpha1 + (size_t)EN_TOT * H1;
  float* alpha2= ez1 + (size_t)EN_TOT * H1;        // EN
  float* ez2   = alpha2 + (size_t)EN_TOT;
  unsigned int* amax1 = (unsigned int*)(ez2 + (size_t)EN_TOT); // N*2
  float* denom1 = (float*)(amax1 + (size_t)N_NODES * H1);
  unsigned int* amax2 = (unsigned int*)(denom1 + (size_t)N_NODES * H1); // N
  float* denom2 = (float*)(amax2 + N_NODES);
  float* deg    = denom2 + N_NODES;
  float* asum   = deg + N_NODES;
  float* lattr  = asum + N_NODES;

  // per-call zero init (accumulators + maxes)
  hipMemsetAsync(deg,    0, sizeof(float) * N_NODES * 2, stream);           // deg + asum (contiguous)
  hipMemsetAsync(amax1,  0, sizeof(unsigned int) * N_NODES * H1, stream);   // fenc(-inf) > 0, 0 is safe min
  hipMemsetAsync(denom1, 0, sizeof(float) * N_NODES * H1, stream);
  hipMemsetAsync(amax2,  0, sizeof(unsigned int) * N_NODES, stream);
  hipMemsetAsync(denom2, 0, sizeof(float) * N_NODES, stream);
  hipMemsetAsync(hacc,   0, sizeof(float) * (size_t)N_NODES * HC1, stream);
  hipMemsetAsync(out,    0, sizeof(float) * (size_t)N_NODES * OUT_DIM, stream);

  const int T = 256;
  // self-loop attrs
  edge_stats_kernel<<<(E_EDGES + T - 1) / T, T, 0, stream>>>(dst, eattr, deg, asum);
  loop_attr_kernel<<<(N_NODES + T - 1) / T, T, 0, stream>>>(deg, asum, lattr);

  // layer 1 GEMMs
  {
    dim3 grid((N_NODES + 63) / 64, HC1 / 64);
    gemm_bias_kernel<64, 64, 16><<<grid, T, 0, stream>>>(x, W1l, b1l, xl1, N_NODES, IN_DIM, HC1);
    gemm_bias_kernel<64, 64, 16><<<grid, T, 0, stream>>>(x, W1r, b1r, xr1, N_NODES, IN_DIM, HC1);
  }
  // layer 1 attention
  alpha1_kernel<<<EN_TOT / 4, T, 0, stream>>>(src, dst, eattr, lattr, xl1, xr1, W1e, att1, alpha1, amax1);
  expdenom_kernel<<<(EN_TOT * H1 + T - 1) / T, T, 0, stream>>>(alpha1, amax1, dst, ez1, denom1, H1);
  scatter1_kernel<<<EN_TOT / 4, T, 0, stream>>>(src, dst, xl1, ez1, denom1, hacc);
  bias_elu_kernel<<<(N_NODES * HC1 + T - 1) / T, T, 0, stream>>>(hacc, bias1);

  // layer 2 GEMMs (input = hacc)
  {
    dim3 grid((N_NODES + 63) / 64, OUT_DIM / 64);
    gemm_bias_kernel<64, 64, 16><<<grid, T, 0, stream>>>(hacc, W2l, b2l, xl2, N_NODES, HC1, OUT_DIM);
    gemm_bias_kernel<64, 64, 16><<<grid, T, 0, stream>>>(hacc, W2r, b2r, xr2, N_NODES, HC1, OUT_DIM);
  }
  // layer 2 attention
  alpha2_kernel<<<EN_TOT / 4, T, 0, stream>>>(src, dst, eattr, lattr, xl2, xr2, W2e, att2, alpha2, amax2);
  expdenom_kernel<<<(EN_TOT + T - 1) / T, T, 0, stream>>>(alpha2, amax2, dst, ez2, denom2, 1);
  scatter2_kernel<<<EN_TOT / 4, T, 0, stream>>>(src, dst, xl2, ez2, denom2, out);
  bias_add_kernel<<<(N_NODES * OUT_DIM + T - 1) / T, T, 0, stream>>>(out, bias2);
}

// Round 2
// 631.247 us; speedup vs baseline: 2.6419x; 2.6419x over previous
//
#include <hip/hip_runtime.h>

#define N_NODES 20000
#define E_EDGES 320000
#define EN_TOT  (E_EDGES + N_NODES)   // edges + self loops = 340000
#define IN_DIM  512
#define H1      2
#define C1      128
#define HC1     256                    // H1*C1
#define OUT_DIM 64

// ---------- tiled fp32 GEMM: C[M,Ncol] = A[M,K] @ B[K,Ncol] + bias ----------
template<int BM, int BN, int BK>
__global__ void gemm_bias_kernel(const float* __restrict__ A, const float* __restrict__ B,
                                 const float* __restrict__ bias, float* __restrict__ C,
                                 int M, int K, int Ncol) {
  __shared__ __align__(16) float As[BK][BM + 1];
  __shared__ __align__(16) float Bs[BK][BN];
  const int bm = blockIdx.x * BM;
  const int bn = blockIdx.y * BN;
  const int tid = threadIdx.x;           // 256 threads
  const int tx = tid & 15, ty = tid >> 4;
  float acc[4][4] = {};
  for (int k0 = 0; k0 < K; k0 += BK) {
    {
      int row = tid >> 2;
      int kk  = (tid & 3) * 4;
      int gr  = bm + row;
      float4 v = make_float4(0.f, 0.f, 0.f, 0.f);
      if (gr < M) v = *reinterpret_cast<const float4*>(A + (size_t)gr * K + k0 + kk);
      As[kk + 0][row] = v.x; As[kk + 1][row] = v.y;
      As[kk + 2][row] = v.z; As[kk + 3][row] = v.w;
    }
    {
      int kr = tid >> 4;
      int cc = (tid & 15) * 4;
      float4 v = *reinterpret_cast<const float4*>(B + (size_t)(k0 + kr) * Ncol + bn + cc);
      *reinterpret_cast<float4*>(&Bs[kr][cc]) = v;
    }
    __syncthreads();
#pragma unroll
    for (int kc = 0; kc < BK; ++kc) {
      float a[4], b[4];
#pragma unroll
      for (int i = 0; i < 4; ++i) a[i] = As[kc][ty * 4 + i];
#pragma unroll
      for (int j = 0; j < 4; ++j) b[j] = Bs[kc][tx * 4 + j];
#pragma unroll
      for (int i = 0; i < 4; ++i)
#pragma unroll
        for (int j = 0; j < 4; ++j)
          acc[i][j] += a[i] * b[j];
    }
    __syncthreads();
  }
#pragma unroll
  for (int i = 0; i < 4; ++i) {
    int gr = bm + ty * 4 + i;
    if (gr >= M) continue;
#pragma unroll
    for (int j = 0; j < 4; ++j) {
      int gc = bn + tx * 4 + j;
      C[(size_t)gr * Ncol + gc] = acc[i][j] + bias[gc];
    }
  }
}

// ---------- edge stats: integer degree + attr sums ----------
__global__ void edge_stats_kernel(const int* __restrict__ dst, const float* __restrict__ eattr,
                                  int* __restrict__ degi, float* __restrict__ asum) {
  int e = blockIdx.x * blockDim.x + threadIdx.x;
  if (e >= E_EDGES) return;
  int d = dst[e];
  atomicAdd(&degi[d], 1);
  atomicAdd(&asum[d], eattr[e]);
}

__global__ void loop_attr_kernel(const int* __restrict__ degi, const float* __restrict__ asum,
                                 float* __restrict__ la) {
  int n = blockIdx.x * blockDim.x + threadIdx.x;
  if (n >= N_NODES) return;
  la[n] = asum[n] / fmaxf((float)degi[n], 1.0f);
}

// ---------- exclusive scan over row lengths (deg+1), single block ----------
__global__ void scan_kernel(const int* __restrict__ degi, int* __restrict__ offs) {
  __shared__ int psum[1024];
  const int T = 1024;
  int tid = threadIdx.x;
  const int per = (N_NODES + T - 1) / T;   // 20
  int base = tid * per;
  int s = 0;
  for (int i = 0; i < per; ++i) {
    int n = base + i;
    if (n < N_NODES) s += degi[n] + 1;     // +1 self loop
  }
  psum[tid] = s;
  __syncthreads();
  for (int off = 1; off < T; off <<= 1) {
    int v = (tid >= off) ? psum[tid - off] : 0;
    __syncthreads();
    psum[tid] += v;
    __syncthreads();
  }
  int run = (tid > 0) ? psum[tid - 1] : 0;  // exclusive
  for (int i = 0; i < per; ++i) {
    int n = base + i;
    if (n < N_NODES) {
      offs[n] = run;
      run += degi[n] + 1;
    }
  }
  if (tid == T - 1) offs[N_NODES] = run;
}

// ---------- CSR fill ----------
__global__ void csr_fill_self_kernel(const int* __restrict__ offs, int* __restrict__ cursor,
                                     int* __restrict__ csr_src, int* __restrict__ csr_eid) {
  int n = blockIdx.x * blockDim.x + threadIdx.x;
  if (n >= N_NODES) return;
  int p = offs[n];
  csr_src[p] = n;
  csr_eid[p] = E_EDGES + n;   // self-loop pseudo edge id
  cursor[n] = 1;
}

__global__ void csr_fill_edges_kernel(const int* __restrict__ src, const int* __restrict__ dst,
                                      const int* __restrict__ offs, int* __restrict__ cursor,
                                      int* __restrict__ csr_src, int* __restrict__ csr_eid) {
  int e = blockIdx.x * blockDim.x + threadIdx.x;
  if (e >= E_EDGES) return;
  int d = dst[e];
  int p = offs[d] + atomicAdd(&cursor[d], 1);
  csr_src[p] = src[e];
  csr_eid[p] = e;
}

// ---------- layer 1 alpha: wave per edge, 256 channels, 2 heads ----------
__global__ void alpha1_kernel(const int* __restrict__ src, const int* __restrict__ dst,
                              const float* __restrict__ eattr, const float* __restrict__ la,
                              const float* __restrict__ xl, const float* __restrict__ xr,
                              const float* __restrict__ We, const float* __restrict__ att,
                              float* __restrict__ alpha) {
  int wid = threadIdx.x >> 6, lane = threadIdx.x & 63;
  int e = blockIdx.x * 4 + wid;             // EN_TOT divisible by 4
  int s, d; float ea;
  if (e < E_EDGES) { s = src[e]; d = dst[e]; ea = eattr[e]; }
  else             { s = d = e - E_EDGES;   ea = la[s]; }
  int c4 = lane * 4;
  float4 vl = *reinterpret_cast<const float4*>(xl + (size_t)s * HC1 + c4);
  float4 vr = *reinterpret_cast<const float4*>(xr + (size_t)d * HC1 + c4);
  float4 ve = *reinterpret_cast<const float4*>(We + c4);
  float4 va = *reinterpret_cast<const float4*>(att + c4);
  float p = 0.f, m;
  m = vl.x + vr.x + ea * ve.x; m = m > 0.f ? m : 0.2f * m; p += m * va.x;
  m = vl.y + vr.y + ea * ve.y; m = m > 0.f ? m : 0.2f * m; p += m * va.y;
  m = vl.z + vr.z + ea * ve.z; m = m > 0.f ? m : 0.2f * m; p += m * va.z;
  m = vl.w + vr.w + ea * ve.w; m = m > 0.f ? m : 0.2f * m; p += m * va.w;
#pragma unroll
  for (int off = 1; off <= 16; off <<= 1) p += __shfl_xor(p, off, 64);
  if (lane == 0 || lane == 32) {
    alpha[(size_t)e * H1 + (lane >> 5)] = p;
  }
}

// ---------- layer 2 alpha: wave per edge, 64 channels, 1 head ----------
__global__ void alpha2_kernel(const int* __restrict__ src, const int* __restrict__ dst,
                              const float* __restrict__ eattr, const float* __restrict__ la,
                              const float* __restrict__ xl, const float* __restrict__ xr,
                              const float* __restrict__ We, const float* __restrict__ att,
                              float* __restrict__ alpha) {
  int wid = threadIdx.x >> 6, lane = threadIdx.x & 63;
  int e = blockIdx.x * 4 + wid;
  int s, d; float ea;
  if (e < E_EDGES) { s = src[e]; d = dst[e]; ea = eattr[e]; }
  else             { s = d = e - E_EDGES;   ea = la[s]; }
  float m = xl[(size_t)s * OUT_DIM + lane] + xr[(size_t)d * OUT_DIM + lane] + ea * We[lane];
  m = m > 0.f ? m : 0.2f * m;
  float p = m * att[lane];
#pragma unroll
  for (int off = 1; off <= 32; off <<= 1) p += __shfl_xor(p, off, 64);
  if (lane == 0) alpha[e] = p;
}

// ---------- layer 1 gather: wave per dst node, softmax + weighted sum + bias + ELU ----------
__global__ void gather1_kernel(const int* __restrict__ offs, const int* __restrict__ csr_src,
                               const int* __restrict__ csr_eid, const float* __restrict__ alpha,
                               const float* __restrict__ xl, const float* __restrict__ bias,
                               float* __restrict__ hout) {
  int wid = threadIdx.x >> 6, lane = threadIdx.x & 63;
  int d = blockIdx.x * 4 + wid;
  if (d >= N_NODES) return;
  int k0 = offs[d], k1 = offs[d + 1];
  int hh = lane >> 5;                       // head for this lane's channels
  // pass A: row max (per head; duplicated across lanes of the head group)
  float mmax = -1e30f;
  for (int k = k0; k < k1; ++k)
    mmax = fmaxf(mmax, alpha[(size_t)csr_eid[k] * H1 + hh]);
  // pass B: denom
  float den = 0.f;
  for (int k = k0; k < k1; ++k)
    den += expf(alpha[(size_t)csr_eid[k] * H1 + hh] - mmax);
  float rden = 1.f / den;
  // pass C: weighted accumulation
  int c4 = lane * 4;
  float4 acc = make_float4(0.f, 0.f, 0.f, 0.f);
  for (int k = k0; k < k1; ++k) {
    int s = csr_src[k];
    float w = expf(alpha[(size_t)csr_eid[k] * H1 + hh] - mmax) * rden;
    float4 v = *reinterpret_cast<const float4*>(xl + (size_t)s * HC1 + c4);
    acc.x += w * v.x; acc.y += w * v.y; acc.z += w * v.z; acc.w += w * v.w;
  }
  float4 b = *reinterpret_cast<const float4*>(bias + c4);
  float4 r;
  r.x = acc.x + b.x; r.y = acc.y + b.y; r.z = acc.z + b.z; r.w = acc.w + b.w;
  r.x = r.x > 0.f ? r.x : expm1f(r.x);
  r.y = r.y > 0.f ? r.y : expm1f(r.y);
  r.z = r.z > 0.f ? r.z : expm1f(r.z);
  r.w = r.w > 0.f ? r.w : expm1f(r.w);
  *reinterpret_cast<float4*>(hout + (size_t)d * HC1 + c4) = r;
}

// ---------- layer 2 gather: wave per dst node, 64 channels, 1 head, + bias ----------
__global__ void gather2_kernel(const int* __restrict__ offs, const int* __restrict__ csr_src,
                               const int* __restrict__ csr_eid, const float* __restrict__ alpha,
                               const float* __restrict__ xl, const float* __restrict__ bias,
                               float* __restrict__ out) {
  int wid = threadIdx.x >> 6, lane = threadIdx.x & 63;
  int d = blockIdx.x * 4 + wid;
  if (d >= N_NODES) return;
  int k0 = offs[d], k1 = offs[d + 1];
  float mmax = -1e30f;
  for (int k = k0; k < k1; ++k)
    mmax = fmaxf(mmax, alpha[csr_eid[k]]);
  float den = 0.f;
  for (int k = k0; k < k1; ++k)
    den += expf(alpha[csr_eid[k]] - mmax);
  float rden = 1.f / den;
  float acc = 0.f;
  for (int k = k0; k < k1; ++k) {
    int s = csr_src[k];
    float w = expf(alpha[csr_eid[k]] - mmax) * rden;
    acc += w * xl[(size_t)s * OUT_DIM + lane];
  }
  out[(size_t)d * OUT_DIM + lane] = acc + bias[lane];
}

extern "C" void kernel_launch(void* const* d_in, const int* in_sizes, int n_in,
                              void* d_out, int out_size, void* d_ws, size_t ws_size,
                              hipStream_t stream) {
  const float* x     = (const float*)d_in[0];
  const int*   ei    = (const int*)d_in[1];
  const float* eattr = (const float*)d_in[2];
  const float* W1l   = (const float*)d_in[3];
  const float* b1l   = (const float*)d_in[4];
  const float* W1r   = (const float*)d_in[5];
  const float* b1r   = (const float*)d_in[6];
  const float* W1e   = (const float*)d_in[7];
  const float* att1  = (const float*)d_in[8];
  const float* bias1 = (const float*)d_in[9];
  const float* W2l   = (const float*)d_in[10];
  const float* b2l   = (const float*)d_in[11];
  const float* W2r   = (const float*)d_in[12];
  const float* b2r   = (const float*)d_in[13];
  const float* W2e   = (const float*)d_in[14];
  const float* att2  = (const float*)d_in[15];
  const float* bias2 = (const float*)d_in[16];
  const int* src = ei;
  const int* dst = ei + E_EDGES;
  float* out = (float*)d_out;

  // workspace layout
  float* ws    = (float*)d_ws;
  float* xl1   = ws;                                  // N*HC1
  float* xr1   = xl1 + (size_t)N_NODES * HC1;         // N*HC1
  float* h     = xr1 + (size_t)N_NODES * HC1;         // N*HC1 (post-ELU)
  float* xl2   = h + (size_t)N_NODES * HC1;           // N*64
  float* xr2   = xl2 + (size_t)N_NODES * OUT_DIM;     // N*64
  float* alpha1= xr2 + (size_t)N_NODES * OUT_DIM;     // EN*2
  float* alpha2= alpha1 + (size_t)EN_TOT * H1;        // EN
  float* asum  = alpha2 + (size_t)EN_TOT;             // N
  float* lattr = asum + N_NODES;                      // N
  int* degi    = (int*)(lattr + N_NODES);             // N
  int* offs    = degi + N_NODES;                      // N+1
  int* cursor  = offs + N_NODES + 1;                  // N
  int* csr_src = cursor + N_NODES;                    // EN
  int* csr_eid = csr_src + EN_TOT;                    // EN

  // per-call zero init
  hipMemsetAsync(degi, 0, sizeof(int) * N_NODES, stream);
  hipMemsetAsync(asum, 0, sizeof(float) * N_NODES, stream);

  const int T = 256;
  // CSR build + self-loop attrs
  edge_stats_kernel<<<(E_EDGES + T - 1) / T, T, 0, stream>>>(dst, eattr, degi, asum);
  loop_attr_kernel<<<(N_NODES + T - 1) / T, T, 0, stream>>>(degi, asum, lattr);
  scan_kernel<<<1, 1024, 0, stream>>>(degi, offs);
  csr_fill_self_kernel<<<(N_NODES + T - 1) / T, T, 0, stream>>>(offs, cursor, csr_src, csr_eid);
  csr_fill_edges_kernel<<<(E_EDGES + T - 1) / T, T, 0, stream>>>(src, dst, offs, cursor, csr_src, csr_eid);

  // layer 1 GEMMs
  {
    dim3 grid((N_NODES + 63) / 64, HC1 / 64);
    gemm_bias_kernel<64, 64, 16><<<grid, T, 0, stream>>>(x, W1l, b1l, xl1, N_NODES, IN_DIM, HC1);
    gemm_bias_kernel<64, 64, 16><<<grid, T, 0, stream>>>(x, W1r, b1r, xr1, N_NODES, IN_DIM, HC1);
  }
  // layer 1 attention
  alpha1_kernel<<<EN_TOT / 4, T, 0, stream>>>(src, dst, eattr, lattr, xl1, xr1, W1e, att1, alpha1);
  gather1_kernel<<<(N_NODES + 3) / 4, T, 0, stream>>>(offs, csr_src, csr_eid, alpha1, xl1, bias1, h);

  // layer 2 GEMMs
  {
    dim3 grid((N_NODES + 63) / 64, OUT_DIM / 64);
    gemm_bias_kernel<64, 64, 16><<<grid, T, 0, stream>>>(h, W2l, b2l, xl2, N_NODES, HC1, OUT_DIM);
    gemm_bias_kernel<64, 64, 16><<<grid, T, 0, stream>>>(h, W2r, b2r, xr2, N_NODES, HC1, OUT_DIM);
  }
  // layer 2 attention
  alpha2_kernel<<<EN_TOT / 4, T, 0, stream>>>(src, dst, eattr, lattr, xl2, xr2, W2e, att2, alpha2);
  gather2_kernel<<<(N_NODES + 3) / 4, T, 0, stream>>>(offs, csr_src, csr_eid, alpha2, xl2, bias2, out);
}

// Round 3
// 453.261 us; speedup vs baseline: 3.6794x; 1.3927x over previous
//
#include <hip/hip_runtime.h>

#define N_NODES 20000
#define E_EDGES 320000
#define EN_TOT  (E_EDGES + N_NODES)   // edges + self loops = 340000
#define IN_DIM  512
#define H1      2
#define C1      128
#define HC1     256                    // H1*C1
#define OUT_DIM 64

typedef __attribute__((ext_vector_type(8))) short short8;
typedef __attribute__((ext_vector_type(4))) float f32x4;

__device__ __forceinline__ unsigned short f2bf(float f) {
  unsigned u = __float_as_uint(f);
  u += 0x7fffu + ((u >> 16) & 1u);    // RNE
  return (unsigned short)(u >> 16);
}
__device__ __forceinline__ float bf2f(unsigned short s) {
  return __uint_as_float(((unsigned)s) << 16);
}

// ---------- x fp32 -> bf16 ----------
__global__ void tobf_kernel(const float* __restrict__ in, unsigned short* __restrict__ out, int n) {
  int i = blockIdx.x * blockDim.x + threadIdx.x;
  if (i * 4 >= n) return;
  float4 v = *reinterpret_cast<const float4*>(in + i * 4);
  ushort4 o;
  o.x = f2bf(v.x); o.y = f2bf(v.y); o.z = f2bf(v.z); o.w = f2bf(v.w);
  *reinterpret_cast<ushort4*>(out + i * 4) = o;
}

// ---------- weight prep: WT[n][k] = bf16(W{l|r}[k][n]), bias concat ----------
__global__ void wprep_kernel(const float* __restrict__ Wl, const float* __restrict__ Wr,
                             const float* __restrict__ bl, const float* __restrict__ br,
                             unsigned short* __restrict__ WT, float* __restrict__ bcat,
                             int K, int Nh) {
  int idx = blockIdx.x * blockDim.x + threadIdx.x;
  int Ntot = 2 * Nh;
  if (idx >= Ntot * K) return;
  int n = idx / K, k = idx - n * K;
  const float* W = (n < Nh) ? Wl : Wr;
  int nn = (n < Nh) ? n : n - Nh;
  WT[idx] = f2bf(W[(size_t)k * Nh + nn]);
  if (idx < Ntot) bcat[idx] = (idx < Nh) ? bl[idx] : br[idx - Nh];
}

// ---------- bf16 MFMA GEMM: C[M,N] = A[M,K] @ BT[N,K]^T + bias, bf16 out ----------
// BM=BN=128, BK=64, 256 threads (4 waves, 2x2), 16x16x32 bf16 MFMA
__global__ __launch_bounds__(256) void gemm_mfma_kernel(
    const unsigned short* __restrict__ A,   // [M][K] bf16
    const unsigned short* __restrict__ BT,  // [N][K] bf16
    const float* __restrict__ bias,         // [N]
    unsigned short* __restrict__ C,         // [M][N] bf16
    int M, int K, int N) {
  constexpr int BM = 128, BK = 64;
  __shared__ short8 AsV[(BK / 8) * BM];   // 16KB, layout [kb][m][8] xor-swizzled
  __shared__ short8 BsV[(BK / 8) * BM];   // 16KB
  const int bm = blockIdx.x * BM;
  const int bn = blockIdx.y * BM;
  const int tid = threadIdx.x;
  const int lane = tid & 63;
  const int wave = tid >> 6;
  const int wr = wave >> 1, wc = wave & 1;   // 2x2 waves of 64x64
  const int lrow = lane & 15, lk = lane >> 4;

  f32x4 acc[4][4] = {};

  for (int k0 = 0; k0 < K; k0 += BK) {
    // stage A: 1024 16B-chunks, 4 per thread
#pragma unroll
    for (int i = 0; i < 4; ++i) {
      int c = tid + i * 256;
      int m = c >> 3, kb = c & 7;
      int gr = bm + m;
      short8 v = {};
      if (gr < M) v = *reinterpret_cast<const short8*>(A + (size_t)gr * K + k0 + kb * 8);
      AsV[((kb << 7) + m) ^ kb] = v;
    }
    // stage BT (N rows guaranteed multiples of 128 here)
#pragma unroll
    for (int i = 0; i < 4; ++i) {
      int c = tid + i * 256;
      int n = c >> 3, kb = c & 7;
      short8 v = *reinterpret_cast<const short8*>(BT + (size_t)(bn + n) * K + k0 + kb * 8);
      BsV[((kb << 7) + n) ^ kb] = v;
    }
    __syncthreads();
#pragma unroll
    for (int ks = 0; ks < 2; ++ks) {
      int kb = ks * 4 + lk;
      short8 a[4], b[4];
#pragma unroll
      for (int mf = 0; mf < 4; ++mf)
        a[mf] = AsV[((kb << 7) + (wr * 64 + mf * 16 + lrow)) ^ kb];
#pragma unroll
      for (int nf = 0; nf < 4; ++nf)
        b[nf] = BsV[((kb << 7) + (wc * 64 + nf * 16 + lrow)) ^ kb];
#pragma unroll
      for (int mf = 0; mf < 4; ++mf)
#pragma unroll
        for (int nf = 0; nf < 4; ++nf)
          acc[mf][nf] = __builtin_amdgcn_mfma_f32_16x16x32_bf16(a[mf], b[nf], acc[mf][nf], 0, 0, 0);
    }
    __syncthreads();
  }
  // epilogue: D[row=(l>>4)*4+r][col=l&15] per 16x16 frag
#pragma unroll
  for (int mf = 0; mf < 4; ++mf) {
#pragma unroll
    for (int r = 0; r < 4; ++r) {
      int row = bm + wr * 64 + mf * 16 + (lane >> 4) * 4 + r;
      if (row >= M) continue;
#pragma unroll
      for (int nf = 0; nf < 4; ++nf) {
        int col = bn + wc * 64 + nf * 16 + (lane & 15);
        C[(size_t)row * N + col] = f2bf(acc[mf][nf][r] + bias[col]);
      }
    }
  }
}

// ---------- edge stats: integer degree + attr sums ----------
__global__ void edge_stats_kernel(const int* __restrict__ dst, const float* __restrict__ eattr,
                                  int* __restrict__ degi, float* __restrict__ asum) {
  int e = blockIdx.x * blockDim.x + threadIdx.x;
  if (e >= E_EDGES) return;
  int d = dst[e];
  atomicAdd(&degi[d], 1);
  atomicAdd(&asum[d], eattr[e]);
}

__global__ void loop_attr_kernel(const int* __restrict__ degi, const float* __restrict__ asum,
                                 float* __restrict__ la) {
  int n = blockIdx.x * blockDim.x + threadIdx.x;
  if (n >= N_NODES) return;
  la[n] = asum[n] / fmaxf((float)degi[n], 1.0f);
}

// ---------- exclusive scan over row lengths (deg+1), single block ----------
__global__ void scan_kernel(const int* __restrict__ degi, int* __restrict__ offs) {
  __shared__ int psum[1024];
  const int T = 1024;
  int tid = threadIdx.x;
  const int per = (N_NODES + T - 1) / T;
  int base = tid * per;
  int s = 0;
  for (int i = 0; i < per; ++i) {
    int n = base + i;
    if (n < N_NODES) s += degi[n] + 1;
  }
  psum[tid] = s;
  __syncthreads();
  for (int off = 1; off < T; off <<= 1) {
    int v = (tid >= off) ? psum[tid - off] : 0;
    __syncthreads();
    psum[tid] += v;
    __syncthreads();
  }
  int run = (tid > 0) ? psum[tid - 1] : 0;
  for (int i = 0; i < per; ++i) {
    int n = base + i;
    if (n < N_NODES) {
      offs[n] = run;
      run += degi[n] + 1;
    }
  }
  if (tid == T - 1) offs[N_NODES] = run;
}

// ---------- CSR fill ----------
__global__ void csr_fill_self_kernel(const int* __restrict__ offs, int* __restrict__ cursor,
                                     int* __restrict__ csr_src, int* __restrict__ csr_eid) {
  int n = blockIdx.x * blockDim.x + threadIdx.x;
  if (n >= N_NODES) return;
  int p = offs[n];
  csr_src[p] = n;
  csr_eid[p] = E_EDGES + n;
  cursor[n] = 1;
}

__global__ void csr_fill_edges_kernel(const int* __restrict__ src, const int* __restrict__ dst,
                                      const int* __restrict__ offs, int* __restrict__ cursor,
                                      int* __restrict__ csr_src, int* __restrict__ csr_eid) {
  int e = blockIdx.x * blockDim.x + threadIdx.x;
  if (e >= E_EDGES) return;
  int d = dst[e];
  int p = offs[d] + atomicAdd(&cursor[d], 1);
  csr_src[p] = src[e];
  csr_eid[p] = e;
}

// ---------- layer 1 alpha: wave per edge, xcat bf16 [N][512] (xl|xr) ----------
__global__ void alpha1_kernel(const int* __restrict__ src, const int* __restrict__ dst,
                              const float* __restrict__ eattr, const float* __restrict__ la,
                              const unsigned short* __restrict__ xc,
                              const float* __restrict__ We, const float* __restrict__ att,
                              float* __restrict__ alpha) {
  int wid = threadIdx.x >> 6, lane = threadIdx.x & 63;
  int e = blockIdx.x * 4 + wid;
  int s, d; float ea;
  if (e < E_EDGES) { s = src[e]; d = dst[e]; ea = eattr[e]; }
  else             { s = d = e - E_EDGES;   ea = la[s]; }
  int c4 = lane * 4;
  ushort4 ul = *reinterpret_cast<const ushort4*>(xc + (size_t)s * 512 + c4);
  ushort4 ur = *reinterpret_cast<const ushort4*>(xc + (size_t)d * 512 + 256 + c4);
  float4 ve = *reinterpret_cast<const float4*>(We + c4);
  float4 va = *reinterpret_cast<const float4*>(att + c4);
  float p = 0.f, m;
  m = bf2f(ul.x) + bf2f(ur.x) + ea * ve.x; m = m > 0.f ? m : 0.2f * m; p += m * va.x;
  m = bf2f(ul.y) + bf2f(ur.y) + ea * ve.y; m = m > 0.f ? m : 0.2f * m; p += m * va.y;
  m = bf2f(ul.z) + bf2f(ur.z) + ea * ve.z; m = m > 0.f ? m : 0.2f * m; p += m * va.z;
  m = bf2f(ul.w) + bf2f(ur.w) + ea * ve.w; m = m > 0.f ? m : 0.2f * m; p += m * va.w;
#pragma unroll
  for (int off = 1; off <= 16; off <<= 1) p += __shfl_xor(p, off, 64);
  if (lane == 0 || lane == 32) alpha[(size_t)e * H1 + (lane >> 5)] = p;
}

// ---------- layer 2 alpha: wave per edge, xc2 bf16 [N][128] (xl|xr) ----------
__global__ void alpha2_kernel(const int* __restrict__ src, const int* __restrict__ dst,
                              const float* __restrict__ eattr, const float* __restrict__ la,
                              const unsigned short* __restrict__ xc2,
                              const float* __restrict__ We, const float* __restrict__ att,
                              float* __restrict__ alpha) {
  int wid = threadIdx.x >> 6, lane = threadIdx.x & 63;
  int e = blockIdx.x * 4 + wid;
  int s, d; float ea;
  if (e < E_EDGES) { s = src[e]; d = dst[e]; ea = eattr[e]; }
  else             { s = d = e - E_EDGES;   ea = la[s]; }
  float m = bf2f(xc2[(size_t)s * 128 + lane]) + bf2f(xc2[(size_t)d * 128 + 64 + lane]) + ea * We[lane];
  m = m > 0.f ? m : 0.2f * m;
  float p = m * att[lane];
#pragma unroll
  for (int off = 1; off <= 32; off <<= 1) p += __shfl_xor(p, off, 64);
  if (lane == 0) alpha[e] = p;
}

// ---------- layer 1 gather: wave per node; softmax + weighted sum + bias + ELU -> bf16 h ----------
__global__ void gather1_kernel(const int* __restrict__ offs, const int* __restrict__ csr_src,
                               const int* __restrict__ csr_eid, const float* __restrict__ alpha,
                               const unsigned short* __restrict__ xc, const float* __restrict__ bias,
                               unsigned short* __restrict__ hout) {
  int wid = threadIdx.x >> 6, lane = threadIdx.x & 63;
  int d = blockIdx.x * 4 + wid;
  if (d >= N_NODES) return;
  int k0 = offs[d], k1 = offs[d + 1];
  int hh = lane >> 5;
  float mmax = -1e30f;
  for (int k = k0; k < k1; ++k)
    mmax = fmaxf(mmax, alpha[(size_t)csr_eid[k] * H1 + hh]);
  float den = 0.f;
  for (int k = k0; k < k1; ++k)
    den += expf(alpha[(size_t)csr_eid[k] * H1 + hh] - mmax);
  float rden = 1.f / den;
  int c4 = lane * 4;
  float4 acc = make_float4(0.f, 0.f, 0.f, 0.f);
  for (int k = k0; k < k1; ++k) {
    int s = csr_src[k];
    float w = expf(alpha[(size_t)csr_eid[k] * H1 + hh] - mmax) * rden;
    ushort4 v = *reinterpret_cast<const ushort4*>(xc + (size_t)s * 512 + c4);
    acc.x += w * bf2f(v.x); acc.y += w * bf2f(v.y);
    acc.z += w * bf2f(v.z); acc.w += w * bf2f(v.w);
  }
  float4 b = *reinterpret_cast<const float4*>(bias + c4);
  float4 r;
  r.x = acc.x + b.x; r.y = acc.y + b.y; r.z = acc.z + b.z; r.w = acc.w + b.w;
  r.x = r.x > 0.f ? r.x : expm1f(r.x);
  r.y = r.y > 0.f ? r.y : expm1f(r.y);
  r.z = r.z > 0.f ? r.z : expm1f(r.z);
  r.w = r.w > 0.f ? r.w : expm1f(r.w);
  ushort4 o;
  o.x = f2bf(r.x); o.y = f2bf(r.y); o.z = f2bf(r.z); o.w = f2bf(r.w);
  *reinterpret_cast<ushort4*>(hout + (size_t)d * HC1 + c4) = o;
}

// ---------- layer 2 gather: wave per node; out fp32 + bias ----------
__global__ void gather2_kernel(const int* __restrict__ offs, const int* __restrict__ csr_src,
                               const int* __restrict__ csr_eid, const float* __restrict__ alpha,
                               const unsigned short* __restrict__ xc2, const float* __restrict__ bias,
                               float* __restrict__ out) {
  int wid = threadIdx.x >> 6, lane = threadIdx.x & 63;
  int d = blockIdx.x * 4 + wid;
  if (d >= N_NODES) return;
  int k0 = offs[d], k1 = offs[d + 1];
  float mmax = -1e30f;
  for (int k = k0; k < k1; ++k)
    mmax = fmaxf(mmax, alpha[csr_eid[k]]);
  float den = 0.f;
  for (int k = k0; k < k1; ++k)
    den += expf(alpha[csr_eid[k]] - mmax);
  float rden = 1.f / den;
  float acc = 0.f;
  for (int k = k0; k < k1; ++k) {
    int s = csr_src[k];
    float w = expf(alpha[csr_eid[k]] - mmax) * rden;
    acc += w * bf2f(xc2[(size_t)s * 128 + lane]);
  }
  out[(size_t)d * OUT_DIM + lane] = acc + bias[lane];
}

extern "C" void kernel_launch(void* const* d_in, const int* in_sizes, int n_in,
                              void* d_out, int out_size, void* d_ws, size_t ws_size,
                              hipStream_t stream) {
  const float* x     = (const float*)d_in[0];
  const int*   ei    = (const int*)d_in[1];
  const float* eattr = (const float*)d_in[2];
  const float* W1l   = (const float*)d_in[3];
  const float* b1l   = (const float*)d_in[4];
  const float* W1r   = (const float*)d_in[5];
  const float* b1r   = (const float*)d_in[6];
  const float* W1e   = (const float*)d_in[7];
  const float* att1  = (const float*)d_in[8];
  const float* bias1 = (const float*)d_in[9];
  const float* W2l   = (const float*)d_in[10];
  const float* b2l   = (const float*)d_in[11];
  const float* W2r   = (const float*)d_in[12];
  const float* b2r   = (const float*)d_in[13];
  const float* W2e   = (const float*)d_in[14];
  const float* att2  = (const float*)d_in[15];
  const float* bias2 = (const float*)d_in[16];
  const int* src = ei;
  const int* dst = ei + E_EDGES;
  float* out = (float*)d_out;

  // workspace layout (bytes)
  char* w = (char*)d_ws;
  unsigned short* xb    = (unsigned short*)w;             w += (size_t)N_NODES * IN_DIM * 2;   // x bf16
  unsigned short* W1T   = (unsigned short*)w;             w += (size_t)IN_DIM * 512 * 2;       // [512][512]
  unsigned short* W2T   = (unsigned short*)w;             w += (size_t)128 * HC1 * 2;          // [128][256]
  unsigned short* xc1   = (unsigned short*)w;             w += (size_t)N_NODES * 512 * 2;      // [N][512] xl|xr bf16
  unsigned short* h     = (unsigned short*)w;             w += (size_t)N_NODES * HC1 * 2;      // [N][256] bf16
  unsigned short* xc2   = (unsigned short*)w;             w += (size_t)N_NODES * 128 * 2;      // [N][128] xl2|xr2 bf16
  float* bcat1  = (float*)w;                              w += 512 * 4;
  float* bcat2  = (float*)w;                              w += 128 * 4;
  float* alpha1 = (float*)w;                              w += (size_t)EN_TOT * H1 * 4;
  float* alpha2 = (float*)w;                              w += (size_t)EN_TOT * 4;
  float* asum   = (float*)w;                              w += (size_t)N_NODES * 4;
  float* lattr  = (float*)w;                              w += (size_t)N_NODES * 4;
  int* degi     = (int*)w;                                w += (size_t)N_NODES * 4;
  int* offs     = (int*)w;                                w += (size_t)(N_NODES + 1) * 4;
  int* cursor   = (int*)w;                                w += (size_t)N_NODES * 4;
  int* csr_src  = (int*)w;                                w += (size_t)EN_TOT * 4;
  int* csr_eid  = (int*)w;                                w += (size_t)EN_TOT * 4;

  hipMemsetAsync(degi, 0, sizeof(int) * N_NODES, stream);
  hipMemsetAsync(asum, 0, sizeof(float) * N_NODES, stream);

  const int T = 256;
  // CSR build + self-loop attrs
  edge_stats_kernel<<<(E_EDGES + T - 1) / T, T, 0, stream>>>(dst, eattr, degi, asum);
  loop_attr_kernel<<<(N_NODES + T - 1) / T, T, 0, stream>>>(degi, asum, lattr);
  scan_kernel<<<1, 1024, 0, stream>>>(degi, offs);
  csr_fill_self_kernel<<<(N_NODES + T - 1) / T, T, 0, stream>>>(offs, cursor, csr_src, csr_eid);
  csr_fill_edges_kernel<<<(E_EDGES + T - 1) / T, T, 0, stream>>>(src, dst, offs, cursor, csr_src, csr_eid);

  // bf16 conversions / weight prep
  tobf_kernel<<<((N_NODES * IN_DIM / 4) + T - 1) / T, T, 0, stream>>>(x, xb, N_NODES * IN_DIM);
  wprep_kernel<<<(512 * 512 + T - 1) / T, T, 0, stream>>>(W1l, W1r, b1l, b1r, W1T, bcat1, IN_DIM, HC1);
  wprep_kernel<<<(128 * 256 + T - 1) / T, T, 0, stream>>>(W2l, W2r, b2l, b2r, W2T, bcat2, HC1, OUT_DIM);

  // layer 1 fused GEMM: [N,512] @ [512,512] -> xc1
  {
    dim3 grid((N_NODES + 127) / 128, 512 / 128);
    gemm_mfma_kernel<<<grid, T, 0, stream>>>(xb, W1T, bcat1, xc1, N_NODES, IN_DIM, 512);
  }
  alpha1_kernel<<<EN_TOT / 4, T, 0, stream>>>(src, dst, eattr, lattr, xc1, W1e, att1, alpha1);
  gather1_kernel<<<(N_NODES + 3) / 4, T, 0, stream>>>(offs, csr_src, csr_eid, alpha1, xc1, bias1, h);

  // layer 2 fused GEMM: [N,256] @ [256,128] -> xc2
  {
    dim3 grid((N_NODES + 127) / 128, 128 / 128);
    gemm_mfma_kernel<<<grid, T, 0, stream>>>(h, W2T, bcat2, xc2, N_NODES, HC1, 128);
  }
  alpha2_kernel<<<EN_TOT / 4, T, 0, stream>>>(src, dst, eattr, lattr, xc2, W2e, att2, alpha2);
  gather2_kernel<<<(N_NODES + 3) / 4, T, 0, stream>>>(offs, csr_src, csr_eid, alpha2, xc2, bias2, out);
}

// Round 4
// 249.929 us; speedup vs baseline: 6.6728x; 1.8136x over previous
//
#include <hip/hip_runtime.h>

#define N_NODES 20000
#define E_EDGES 320000
#define EN_TOT  (E_EDGES + N_NODES)   // edges + self loops = 340000
#define IN_DIM  512
#define H1      2
#define C1      128
#define HC1     256                    // H1*C1
#define OUT_DIM 64

typedef __attribute__((ext_vector_type(8))) short short8;
typedef __attribute__((ext_vector_type(4))) float f32x4;

__device__ __forceinline__ unsigned short f2bf(float f) {
  unsigned u = __float_as_uint(f);
  u += 0x7fffu + ((u >> 16) & 1u);    // RNE
  return (unsigned short)(u >> 16);
}
__device__ __forceinline__ float bf2f(unsigned short s) {
  return __uint_as_float(((unsigned)s) << 16);
}

// ---------- x fp32 -> bf16 ----------
__global__ void tobf_kernel(const float* __restrict__ in, unsigned short* __restrict__ out, int n) {
  int i = blockIdx.x * blockDim.x + threadIdx.x;
  if (i * 4 >= n) return;
  float4 v = *reinterpret_cast<const float4*>(in + i * 4);
  ushort4 o;
  o.x = f2bf(v.x); o.y = f2bf(v.y); o.z = f2bf(v.z); o.w = f2bf(v.w);
  *reinterpret_cast<ushort4*>(out + i * 4) = o;
}

// ---------- weight prep: WT[n][k] = bf16(W{l|r}[k][n]), bias concat ----------
__global__ void wprep_kernel(const float* __restrict__ Wl, const float* __restrict__ Wr,
                             const float* __restrict__ bl, const float* __restrict__ br,
                             unsigned short* __restrict__ WT, float* __restrict__ bcat,
                             int K, int Nh) {
  int idx = blockIdx.x * blockDim.x + threadIdx.x;
  int Ntot = 2 * Nh;
  if (idx >= Ntot * K) return;
  int n = idx / K, k = idx - n * K;
  const float* W = (n < Nh) ? Wl : Wr;
  int nn = (n < Nh) ? n : n - Nh;
  WT[idx] = f2bf(W[(size_t)k * Nh + nn]);
  if (idx < Ntot) bcat[idx] = (idx < Nh) ? bl[idx] : br[idx - Nh];
}

// ---------- bf16 MFMA GEMM: C[M,N] = A[M,K] @ BT[N,K]^T + bias, bf16 out ----------
__global__ __launch_bounds__(256) void gemm_mfma_kernel(
    const unsigned short* __restrict__ A,   // [M][K] bf16
    const unsigned short* __restrict__ BT,  // [N][K] bf16
    const float* __restrict__ bias,         // [N]
    unsigned short* __restrict__ C,         // [M][N] bf16
    int M, int K, int N) {
  constexpr int BM = 128, BK = 64;
  __shared__ short8 AsV[(BK / 8) * BM];   // 16KB, [kb][m] xor-swizzled
  __shared__ short8 BsV[(BK / 8) * BM];   // 16KB
  const int bm = blockIdx.x * BM;
  const int bn = blockIdx.y * BM;
  const int tid = threadIdx.x;
  const int lane = tid & 63;
  const int wave = tid >> 6;
  const int wr = wave >> 1, wc = wave & 1;   // 2x2 waves of 64x64
  const int lrow = lane & 15, lk = lane >> 4;

  f32x4 acc[4][4] = {};

  for (int k0 = 0; k0 < K; k0 += BK) {
#pragma unroll
    for (int i = 0; i < 4; ++i) {
      int c = tid + i * 256;
      int m = c >> 3, kb = c & 7;
      int gr = bm + m;
      short8 v = {};
      if (gr < M) v = *reinterpret_cast<const short8*>(A + (size_t)gr * K + k0 + kb * 8);
      AsV[((kb << 7) + m) ^ kb] = v;
    }
#pragma unroll
    for (int i = 0; i < 4; ++i) {
      int c = tid + i * 256;
      int n = c >> 3, kb = c & 7;
      short8 v = *reinterpret_cast<const short8*>(BT + (size_t)(bn + n) * K + k0 + kb * 8);
      BsV[((kb << 7) + n) ^ kb] = v;
    }
    __syncthreads();
#pragma unroll
    for (int ks = 0; ks < 2; ++ks) {
      int kb = ks * 4 + lk;
      short8 a[4], b[4];
#pragma unroll
      for (int mf = 0; mf < 4; ++mf)
        a[mf] = AsV[((kb << 7) + (wr * 64 + mf * 16 + lrow)) ^ kb];
#pragma unroll
      for (int nf = 0; nf < 4; ++nf)
        b[nf] = BsV[((kb << 7) + (wc * 64 + nf * 16 + lrow)) ^ kb];
#pragma unroll
      for (int mf = 0; mf < 4; ++mf)
#pragma unroll
        for (int nf = 0; nf < 4; ++nf)
          acc[mf][nf] = __builtin_amdgcn_mfma_f32_16x16x32_bf16(a[mf], b[nf], acc[mf][nf], 0, 0, 0);
    }
    __syncthreads();
  }
#pragma unroll
  for (int mf = 0; mf < 4; ++mf) {
#pragma unroll
    for (int r = 0; r < 4; ++r) {
      int row = bm + wr * 64 + mf * 16 + (lane >> 4) * 4 + r;
      if (row >= M) continue;
#pragma unroll
      for (int nf = 0; nf < 4; ++nf) {
        int col = bn + wc * 64 + nf * 16 + (lane & 15);
        C[(size_t)row * N + col] = f2bf(acc[mf][nf][r] + bias[col]);
      }
    }
  }
}

// ---------- edge stats: integer degree + attr sums ----------
__global__ void edge_stats_kernel(const int* __restrict__ dst, const float* __restrict__ eattr,
                                  int* __restrict__ degi, float* __restrict__ asum) {
  int e = blockIdx.x * blockDim.x + threadIdx.x;
  if (e >= E_EDGES) return;
  int d = dst[e];
  atomicAdd(&degi[d], 1);
  atomicAdd(&asum[d], eattr[e]);
}

__global__ void loop_attr_kernel(const int* __restrict__ degi, const float* __restrict__ asum,
                                 float* __restrict__ la) {
  int n = blockIdx.x * blockDim.x + threadIdx.x;
  if (n >= N_NODES) return;
  la[n] = asum[n] / fmaxf((float)degi[n], 1.0f);
}

// ---------- exclusive scan over row lengths (deg+1), single block ----------
__global__ void scan_kernel(const int* __restrict__ degi, int* __restrict__ offs) {
  __shared__ int psum[1024];
  const int T = 1024;
  int tid = threadIdx.x;
  const int per = (N_NODES + T - 1) / T;
  int base = tid * per;
  int s = 0;
  for (int i = 0; i < per; ++i) {
    int n = base + i;
    if (n < N_NODES) s += degi[n] + 1;
  }
  psum[tid] = s;
  __syncthreads();
  for (int off = 1; off < T; off <<= 1) {
    int v = (tid >= off) ? psum[tid - off] : 0;
    __syncthreads();
    psum[tid] += v;
    __syncthreads();
  }
  int run = (tid > 0) ? psum[tid - 1] : 0;
  for (int i = 0; i < per; ++i) {
    int n = base + i;
    if (n < N_NODES) {
      offs[n] = run;
      run += degi[n] + 1;
    }
  }
  if (tid == T - 1) offs[N_NODES] = run;
}

// ---------- CSR fill: src node + edge attr value per slot ----------
__global__ void csr_fill_self_kernel(const int* __restrict__ offs, const float* __restrict__ la,
                                     int* __restrict__ cursor,
                                     int* __restrict__ csr_src, float* __restrict__ csr_ea) {
  int n = blockIdx.x * blockDim.x + threadIdx.x;
  if (n >= N_NODES) return;
  int p = offs[n];
  csr_src[p] = n;
  csr_ea[p] = la[n];
  cursor[n] = 1;
}

__global__ void csr_fill_edges_kernel(const int* __restrict__ src, const int* __restrict__ dst,
                                      const float* __restrict__ eattr,
                                      const int* __restrict__ offs, int* __restrict__ cursor,
                                      int* __restrict__ csr_src, float* __restrict__ csr_ea) {
  int e = blockIdx.x * blockDim.x + threadIdx.x;
  if (e >= E_EDGES) return;
  int d = dst[e];
  int p = offs[d] + atomicAdd(&cursor[d], 1);
  csr_src[p] = src[e];
  csr_ea[p] = eattr[e];
}

// ---------- fused layer 1: wave per node, online softmax + aggregate + bias + ELU ----------
// xc layout per row: [xl(256) | xr(256)], heads: ch 0-127 = head0, 128-255 = head1
__global__ __launch_bounds__(256) void fused1_kernel(
    const int* __restrict__ offs, const int* __restrict__ csr_src, const float* __restrict__ csr_ea,
    const unsigned short* __restrict__ xc, const float* __restrict__ We, const float* __restrict__ att,
    const float* __restrict__ bias, unsigned short* __restrict__ hout) {
  int wid = threadIdx.x >> 6, lane = threadIdx.x & 63;
  int d = blockIdx.x * 4 + wid;
  if (d >= N_NODES) return;
  const int c4 = lane * 4;
  // hoist per-node row + weights into registers
  ushort4 ur = *reinterpret_cast<const ushort4*>(xc + (size_t)d * 512 + 256 + c4);
  float xr0 = bf2f(ur.x), xr1 = bf2f(ur.y), xr2 = bf2f(ur.z), xr3 = bf2f(ur.w);
  float4 ve = *reinterpret_cast<const float4*>(We + c4);
  float4 va = *reinterpret_cast<const float4*>(att + c4);
  int k0 = offs[d], k1 = offs[d + 1];
  float mmax = -1e30f, den = 0.f;
  float a0 = 0.f, a1 = 0.f, a2 = 0.f, a3 = 0.f;
  for (int kb = k0; kb < k1; kb += 64) {
    int nk = min(64, k1 - kb);
    int sv = 0; float eav = 0.f;
    if (lane < nk) { sv = csr_src[kb + lane]; eav = csr_ea[kb + lane]; }
    for (int j = 0; j < nk; ++j) {
      int   s  = __shfl(sv, j);
      float ea = __shfl(eav, j);
      ushort4 ul = *reinterpret_cast<const ushort4*>(xc + (size_t)s * 512 + c4);
      float x0 = bf2f(ul.x), x1 = bf2f(ul.y), x2 = bf2f(ul.z), x3 = bf2f(ul.w);
      float m, p;
      m = x0 + xr0 + ea * ve.x; m = m > 0.f ? m : 0.2f * m; p  = m * va.x;
      m = x1 + xr1 + ea * ve.y; m = m > 0.f ? m : 0.2f * m; p += m * va.y;
      m = x2 + xr2 + ea * ve.z; m = m > 0.f ? m : 0.2f * m; p += m * va.z;
      m = x3 + xr3 + ea * ve.w; m = m > 0.f ? m : 0.2f * m; p += m * va.w;
#pragma unroll
      for (int off = 1; off <= 16; off <<= 1) p += __shfl_xor(p, off, 64);
      // online softmax update (per half-wave = per head)
      float nm = fmaxf(mmax, p);
      float corr = expf(mmax - nm);
      float w = expf(p - nm);
      den = den * corr + w;
      a0 = a0 * corr + w * x0;
      a1 = a1 * corr + w * x1;
      a2 = a2 * corr + w * x2;
      a3 = a3 * corr + w * x3;
      mmax = nm;
    }
  }
  float rden = 1.f / den;
  float4 b = *reinterpret_cast<const float4*>(bias + c4);
  float r0 = a0 * rden + b.x; r0 = r0 > 0.f ? r0 : expm1f(r0);
  float r1 = a1 * rden + b.y; r1 = r1 > 0.f ? r1 : expm1f(r1);
  float r2 = a2 * rden + b.z; r2 = r2 > 0.f ? r2 : expm1f(r2);
  float r3 = a3 * rden + b.w; r3 = r3 > 0.f ? r3 : expm1f(r3);
  ushort4 o;
  o.x = f2bf(r0); o.y = f2bf(r1); o.z = f2bf(r2); o.w = f2bf(r3);
  *reinterpret_cast<ushort4*>(hout + (size_t)d * HC1 + c4) = o;
}

// ---------- fused layer 2: wave per node, 64 channels, 1 head, fp32 out ----------
// xc2 layout per row: [xl(64) | xr(64)]
__global__ __launch_bounds__(256) void fused2_kernel(
    const int* __restrict__ offs, const int* __restrict__ csr_src, const float* __restrict__ csr_ea,
    const unsigned short* __restrict__ xc2, const float* __restrict__ We, const float* __restrict__ att,
    const float* __restrict__ bias, float* __restrict__ out) {
  int wid = threadIdx.x >> 6, lane = threadIdx.x & 63;
  int d = blockIdx.x * 4 + wid;
  if (d >= N_NODES) return;
  float xr = bf2f(xc2[(size_t)d * 128 + 64 + lane]);
  float ve = We[lane];
  float va = att[lane];
  int k0 = offs[d], k1 = offs[d + 1];
  float mmax = -1e30f, den = 0.f, acc = 0.f;
  for (int kb = k0; kb < k1; kb += 64) {
    int nk = min(64, k1 - kb);
    int sv = 0; float eav = 0.f;
    if (lane < nk) { sv = csr_src[kb + lane]; eav = csr_ea[kb + lane]; }
    for (int j = 0; j < nk; ++j) {
      int   s  = __shfl(sv, j);
      float ea = __shfl(eav, j);
      float x = bf2f(xc2[(size_t)s * 128 + lane]);
      float m = x + xr + ea * ve;
      m = m > 0.f ? m : 0.2f * m;
      float p = m * va;
#pragma unroll
      for (int off = 1; off <= 32; off <<= 1) p += __shfl_xor(p, off, 64);
      float nm = fmaxf(mmax, p);
      float corr = expf(mmax - nm);
      float w = expf(p - nm);
      den = den * corr + w;
      acc = acc * corr + w * x;
      mmax = nm;
    }
  }
  out[(size_t)d * OUT_DIM + lane] = acc / den + bias[lane];
}

extern "C" void kernel_launch(void* const* d_in, const int* in_sizes, int n_in,
                              void* d_out, int out_size, void* d_ws, size_t ws_size,
                              hipStream_t stream) {
  const float* x     = (const float*)d_in[0];
  const int*   ei    = (const int*)d_in[1];
  const float* eattr = (const float*)d_in[2];
  const float* W1l   = (const float*)d_in[3];
  const float* b1l   = (const float*)d_in[4];
  const float* W1r   = (const float*)d_in[5];
  const float* b1r   = (const float*)d_in[6];
  const float* W1e   = (const float*)d_in[7];
  const float* att1  = (const float*)d_in[8];
  const float* bias1 = (const float*)d_in[9];
  const float* W2l   = (const float*)d_in[10];
  const float* b2l   = (const float*)d_in[11];
  const float* W2r   = (const float*)d_in[12];
  const float* b2r   = (const float*)d_in[13];
  const float* W2e   = (const float*)d_in[14];
  const float* att2  = (const float*)d_in[15];
  const float* bias2 = (const float*)d_in[16];
  const int* src = ei;
  const int* dst = ei + E_EDGES;
  float* out = (float*)d_out;

  // workspace layout (bytes)
  char* w = (char*)d_ws;
  unsigned short* xb    = (unsigned short*)w;             w += (size_t)N_NODES * IN_DIM * 2;
  unsigned short* W1T   = (unsigned short*)w;             w += (size_t)IN_DIM * 512 * 2;
  unsigned short* W2T   = (unsigned short*)w;             w += (size_t)128 * HC1 * 2;
  unsigned short* xc1   = (unsigned short*)w;             w += (size_t)N_NODES * 512 * 2;
  unsigned short* h     = (unsigned short*)w;             w += (size_t)N_NODES * HC1 * 2;
  unsigned short* xc2   = (unsigned short*)w;             w += (size_t)N_NODES * 128 * 2;
  float* bcat1  = (float*)w;                              w += 512 * 4;
  float* bcat2  = (float*)w;                              w += 128 * 4;
  float* asum   = (float*)w;                              w += (size_t)N_NODES * 4;
  float* lattr  = (float*)w;                              w += (size_t)N_NODES * 4;
  int* degi     = (int*)w;                                w += (size_t)N_NODES * 4;
  int* offs     = (int*)w;                                w += (size_t)(N_NODES + 1) * 4;
  int* cursor   = (int*)w;                                w += (size_t)N_NODES * 4;
  int* csr_src  = (int*)w;                                w += (size_t)EN_TOT * 4;
  float* csr_ea = (float*)w;                              w += (size_t)EN_TOT * 4;

  hipMemsetAsync(degi, 0, sizeof(int) * N_NODES, stream);
  hipMemsetAsync(asum, 0, sizeof(float) * N_NODES, stream);

  const int T = 256;
  // CSR build + self-loop attrs
  edge_stats_kernel<<<(E_EDGES + T - 1) / T, T, 0, stream>>>(dst, eattr, degi, asum);
  loop_attr_kernel<<<(N_NODES + T - 1) / T, T, 0, stream>>>(degi, asum, lattr);
  scan_kernel<<<1, 1024, 0, stream>>>(degi, offs);
  csr_fill_self_kernel<<<(N_NODES + T - 1) / T, T, 0, stream>>>(offs, lattr, cursor, csr_src, csr_ea);
  csr_fill_edges_kernel<<<(E_EDGES + T - 1) / T, T, 0, stream>>>(src, dst, eattr, offs, cursor, csr_src, csr_ea);

  // bf16 conversions / weight prep
  tobf_kernel<<<((N_NODES * IN_DIM / 4) + T - 1) / T, T, 0, stream>>>(x, xb, N_NODES * IN_DIM);
  wprep_kernel<<<(512 * 512 + T - 1) / T, T, 0, stream>>>(W1l, W1r, b1l, b1r, W1T, bcat1, IN_DIM, HC1);
  wprep_kernel<<<(128 * 256 + T - 1) / T, T, 0, stream>>>(W2l, W2r, b2l, b2r, W2T, bcat2, HC1, OUT_DIM);

  // layer 1: fused GEMM [N,512]@[512,512] -> xc1, then fused edge phase
  {
    dim3 grid((N_NODES + 127) / 128, 512 / 128);
    gemm_mfma_kernel<<<grid, T, 0, stream>>>(xb, W1T, bcat1, xc1, N_NODES, IN_DIM, 512);
  }
  fused1_kernel<<<(N_NODES + 3) / 4, T, 0, stream>>>(offs, csr_src, csr_ea, xc1, W1e, att1, bias1, h);

  // layer 2: fused GEMM [N,256]@[256,128] -> xc2, then fused edge phase
  {
    dim3 grid((N_NODES + 127) / 128, 128 / 128);
    gemm_mfma_kernel<<<grid, T, 0, stream>>>(h, W2T, bcat2, xc2, N_NODES, HC1, 128);
  }
  fused2_kernel<<<(N_NODES + 3) / 4, T, 0, stream>>>(offs, csr_src, csr_ea, xc2, W2e, att2, bias2, out);
}

// Round 5
// 231.083 us; speedup vs baseline: 7.2170x; 1.0816x over previous
//
#include <hip/hip_runtime.h>

#define N_NODES 20000
#define E_EDGES 320000
#define EN_TOT  (E_EDGES + N_NODES)   // edges + self loops = 340000
#define IN_DIM  512
#define H1      2
#define C1      128
#define HC1     256                    // H1*C1
#define OUT_DIM 64

typedef __attribute__((ext_vector_type(8))) short short8;
typedef __attribute__((ext_vector_type(4))) float f32x4;

__device__ __forceinline__ unsigned short f2bf(float f) {
  unsigned u = __float_as_uint(f);
  u += 0x7fffu + ((u >> 16) & 1u);    // RNE
  return (unsigned short)(u >> 16);
}
__device__ __forceinline__ float bf2f(unsigned short s) {
  return __uint_as_float(((unsigned)s) << 16);
}

// ---------- merged prep: x->bf16, W1 transpose+concat, W2 transpose+concat ----------
__global__ void prep_kernel(const float* __restrict__ x, unsigned short* __restrict__ xb,
                            const float* __restrict__ W1l, const float* __restrict__ W1r,
                            const float* __restrict__ b1l, const float* __restrict__ b1r,
                            unsigned short* __restrict__ W1T, float* __restrict__ bcat1,
                            const float* __restrict__ W2l, const float* __restrict__ W2r,
                            const float* __restrict__ b2l, const float* __restrict__ b2r,
                            unsigned short* __restrict__ W2T, float* __restrict__ bcat2) {
  int idx = blockIdx.x * blockDim.x + threadIdx.x;
  const int A  = N_NODES * IN_DIM / 4;   // 2,560,000 threads, 4 elems each
  const int B1 = 512 * 512;
  const int B2 = 128 * 256;
  if (idx < A) {
    float4 v = *reinterpret_cast<const float4*>(x + (size_t)idx * 4);
    ushort4 o;
    o.x = f2bf(v.x); o.y = f2bf(v.y); o.z = f2bf(v.z); o.w = f2bf(v.w);
    *reinterpret_cast<ushort4*>(xb + (size_t)idx * 4) = o;
  } else if (idx < A + B1) {
    int t = idx - A;                 // n*512 + k, n in [0,512)
    int n = t >> 9, k = t & 511;
    const float* W = (n < 256) ? W1l : W1r;
    int nn = n & 255;
    W1T[t] = f2bf(W[(size_t)k * 256 + nn]);
    if (k == 0) bcat1[n] = (n < 256) ? b1l[nn] : b1r[nn];
  } else if (idx < A + B1 + B2) {
    int t = idx - A - B1;            // n*256 + k, n in [0,128)
    int n = t >> 8, k = t & 255;
    const float* W = (n < 64) ? W2l : W2r;
    int nn = n & 63;
    W2T[t] = f2bf(W[(size_t)k * 64 + nn]);
    if (k == 0) bcat2[n] = (n < 64) ? b2l[nn] : b2r[nn];
  }
}

// ---------- bf16 MFMA GEMM: C[M,N] = A[M,K] @ BT[N,K]^T + bias, bf16 out ----------
__global__ __launch_bounds__(256) void gemm_mfma_kernel(
    const unsigned short* __restrict__ A,   // [M][K] bf16
    const unsigned short* __restrict__ BT,  // [N][K] bf16
    const float* __restrict__ bias,         // [N]
    unsigned short* __restrict__ C,         // [M][N] bf16
    int M, int K, int N) {
  constexpr int BM = 128, BK = 64;
  __shared__ short8 AsV[(BK / 8) * BM];   // 16KB, [kb][m] xor-swizzled
  __shared__ short8 BsV[(BK / 8) * BM];   // 16KB
  const int bm = blockIdx.x * BM;
  const int bn = blockIdx.y * BM;
  const int tid = threadIdx.x;
  const int lane = tid & 63;
  const int wave = tid >> 6;
  const int wr = wave >> 1, wc = wave & 1;   // 2x2 waves of 64x64
  const int lrow = lane & 15, lk = lane >> 4;

  f32x4 acc[4][4] = {};

  for (int k0 = 0; k0 < K; k0 += BK) {
#pragma unroll
    for (int i = 0; i < 4; ++i) {
      int c = tid + i * 256;
      int m = c >> 3, kb = c & 7;
      int gr = bm + m;
      short8 v = {};
      if (gr < M) v = *reinterpret_cast<const short8*>(A + (size_t)gr * K + k0 + kb * 8);
      AsV[((kb << 7) + m) ^ kb] = v;
    }
#pragma unroll
    for (int i = 0; i < 4; ++i) {
      int c = tid + i * 256;
      int n = c >> 3, kb = c & 7;
      short8 v = *reinterpret_cast<const short8*>(BT + (size_t)(bn + n) * K + k0 + kb * 8);
      BsV[((kb << 7) + n) ^ kb] = v;
    }
    __syncthreads();
#pragma unroll
    for (int ks = 0; ks < 2; ++ks) {
      int kb = ks * 4 + lk;
      short8 a[4], b[4];
#pragma unroll
      for (int mf = 0; mf < 4; ++mf)
        a[mf] = AsV[((kb << 7) + (wr * 64 + mf * 16 + lrow)) ^ kb];
#pragma unroll
      for (int nf = 0; nf < 4; ++nf)
        b[nf] = BsV[((kb << 7) + (wc * 64 + nf * 16 + lrow)) ^ kb];
#pragma unroll
      for (int mf = 0; mf < 4; ++mf)
#pragma unroll
        for (int nf = 0; nf < 4; ++nf)
          acc[mf][nf] = __builtin_amdgcn_mfma_f32_16x16x32_bf16(a[mf], b[nf], acc[mf][nf], 0, 0, 0);
    }
    __syncthreads();
  }
#pragma unroll
  for (int mf = 0; mf < 4; ++mf) {
#pragma unroll
    for (int r = 0; r < 4; ++r) {
      int row = bm + wr * 64 + mf * 16 + (lane >> 4) * 4 + r;
      if (row >= M) continue;
#pragma unroll
      for (int nf = 0; nf < 4; ++nf) {
        int col = bn + wc * 64 + nf * 16 + (lane & 15);
        C[(size_t)row * N + col] = f2bf(acc[mf][nf][r] + bias[col]);
      }
    }
  }
}

// ---------- edge stats: integer degree + attr sums ----------
__global__ void edge_stats_kernel(const int* __restrict__ dst, const float* __restrict__ eattr,
                                  int* __restrict__ degi, float* __restrict__ asum) {
  int e = blockIdx.x * blockDim.x + threadIdx.x;
  if (e >= E_EDGES) return;
  int d = dst[e];
  atomicAdd(&degi[d], 1);
  atomicAdd(&asum[d], eattr[e]);
}

// ---------- exclusive scan over row lengths (deg+1), single block ----------
__global__ void scan_kernel(const int* __restrict__ degi, int* __restrict__ offs) {
  __shared__ int psum[1024];
  const int T = 1024;
  int tid = threadIdx.x;
  const int per = (N_NODES + T - 1) / T;
  int base = tid * per;
  int s = 0;
  for (int i = 0; i < per; ++i) {
    int n = base + i;
    if (n < N_NODES) s += degi[n] + 1;
  }
  psum[tid] = s;
  __syncthreads();
  for (int off = 1; off < T; off <<= 1) {
    int v = (tid >= off) ? psum[tid - off] : 0;
    __syncthreads();
    psum[tid] += v;
    __syncthreads();
  }
  int run = (tid > 0) ? psum[tid - 1] : 0;
  for (int i = 0; i < per; ++i) {
    int n = base + i;
    if (n < N_NODES) {
      offs[n] = run;
      run += degi[n] + 1;
    }
  }
  if (tid == T - 1) offs[N_NODES] = run;
}

// ---------- CSR fill: interleaved (src, eattr-bits); self slot also computes loop attr ----------
__global__ void csr_fill_self_kernel(const int* __restrict__ offs, const int* __restrict__ degi,
                                     const float* __restrict__ asum, int* __restrict__ cursor,
                                     int2* __restrict__ csr) {
  int n = blockIdx.x * blockDim.x + threadIdx.x;
  if (n >= N_NODES) return;
  float la = asum[n] / fmaxf((float)degi[n], 1.0f);
  csr[offs[n]] = make_int2(n, __float_as_int(la));
  cursor[n] = 1;
}

__global__ void csr_fill_edges_kernel(const int* __restrict__ src, const int* __restrict__ dst,
                                      const float* __restrict__ eattr,
                                      const int* __restrict__ offs, int* __restrict__ cursor,
                                      int2* __restrict__ csr) {
  int e = blockIdx.x * blockDim.x + threadIdx.x;
  if (e >= E_EDGES) return;
  int d = dst[e];
  int p = offs[d] + atomicAdd(&cursor[d], 1);
  csr[p] = make_int2(src[e], __float_as_int(eattr[e]));
}

// ---------- fused layer 1: wave per node, online softmax + aggregate + bias + ELU ----------
// xc layout per row: [xl(256) | xr(256)]; lanes 0-31 = head0 (ch 0-127), 32-63 = head1
__global__ __launch_bounds__(256) void fused1_kernel(
    const int* __restrict__ offs, const int2* __restrict__ csr,
    const unsigned short* __restrict__ xc, const float* __restrict__ We,
    const float* __restrict__ att, const float* __restrict__ bias,
    unsigned short* __restrict__ hout) {
  int wid = threadIdx.x >> 6, lane = threadIdx.x & 63;
  int d = blockIdx.x * 4 + wid;
  if (d >= N_NODES) return;
  const int c4 = lane * 4;
  ushort4 ur = *reinterpret_cast<const ushort4*>(xc + (size_t)d * 512 + 256 + c4);
  float xr0 = bf2f(ur.x), xr1 = bf2f(ur.y), xr2 = bf2f(ur.z), xr3 = bf2f(ur.w);
  float4 ve = *reinterpret_cast<const float4*>(We + c4);
  float4 va = *reinterpret_cast<const float4*>(att + c4);
  int k0 = offs[d], k1 = offs[d + 1];
  float mmax = -1e30f, den = 0.f;
  float a0 = 0.f, a1 = 0.f, a2 = 0.f, a3 = 0.f;
  for (int kb = k0; kb < k1; kb += 64) {
    int nk = min(64, k1 - kb);
    int2 ce = make_int2(0, 0);
    if (lane < nk) ce = csr[kb + lane];
    for (int j = 0; j < nk; ++j) {
      int   s  = __shfl(ce.x, j);
      float ea = __int_as_float(__shfl(ce.y, j));
      ushort4 ul = *reinterpret_cast<const ushort4*>(xc + (size_t)s * 512 + c4);
      float x0 = bf2f(ul.x), x1 = bf2f(ul.y), x2 = bf2f(ul.z), x3 = bf2f(ul.w);
      // m = x + (xr + ea*We); leaky = max(m,0) + 0.2*min(m,0)
      float m0 = x0 + fmaf(ea, ve.x, xr0);
      float m1 = x1 + fmaf(ea, ve.y, xr1);
      float m2 = x2 + fmaf(ea, ve.z, xr2);
      float m3 = x3 + fmaf(ea, ve.w, xr3);
      m0 = fmaf(0.2f, fminf(m0, 0.f), fmaxf(m0, 0.f));
      m1 = fmaf(0.2f, fminf(m1, 0.f), fmaxf(m1, 0.f));
      m2 = fmaf(0.2f, fminf(m2, 0.f), fmaxf(m2, 0.f));
      m3 = fmaf(0.2f, fminf(m3, 0.f), fmaxf(m3, 0.f));
      float p = fmaf(m0, va.x, m1 * va.y) + fmaf(m2, va.z, m3 * va.w);
#pragma unroll
      for (int off = 1; off <= 16; off <<= 1) p += __shfl_xor(p, off, 64);
      // one-exp online softmax update
      float hi = fmaxf(mmax, p);
      float lo = fminf(mmax, p);
      float t  = __expf(lo - hi);
      bool  up = p > mmax;
      float corr = up ? t : 1.0f;
      float w    = up ? 1.0f : t;
      den = fmaf(den, corr, w);
      a0 = fmaf(a0, corr, w * x0);
      a1 = fmaf(a1, corr, w * x1);
      a2 = fmaf(a2, corr, w * x2);
      a3 = fmaf(a3, corr, w * x3);
      mmax = hi;
    }
  }
  float rden = 1.f / den;
  float4 b = *reinterpret_cast<const float4*>(bias + c4);
  float r0 = fmaf(a0, rden, b.x); r0 = r0 > 0.f ? r0 : expm1f(r0);
  float r1 = fmaf(a1, rden, b.y); r1 = r1 > 0.f ? r1 : expm1f(r1);
  float r2 = fmaf(a2, rden, b.z); r2 = r2 > 0.f ? r2 : expm1f(r2);
  float r3 = fmaf(a3, rden, b.w); r3 = r3 > 0.f ? r3 : expm1f(r3);
  ushort4 o;
  o.x = f2bf(r0); o.y = f2bf(r1); o.z = f2bf(r2); o.w = f2bf(r3);
  *reinterpret_cast<ushort4*>(hout + (size_t)d * HC1 + c4) = o;
}

// ---------- fused layer 2: wave per node, 64 channels, 1 head, fp32 out ----------
// xc2 layout per row: [xl(64) | xr(64)]
__global__ __launch_bounds__(256) void fused2_kernel(
    const int* __restrict__ offs, const int2* __restrict__ csr,
    const unsigned short* __restrict__ xc2, const float* __restrict__ We,
    const float* __restrict__ att, const float* __restrict__ bias,
    float* __restrict__ out) {
  int wid = threadIdx.x >> 6, lane = threadIdx.x & 63;
  int d = blockIdx.x * 4 + wid;
  if (d >= N_NODES) return;
  float xr = bf2f(xc2[(size_t)d * 128 + 64 + lane]);
  float ve = We[lane];
  float va = att[lane];
  int k0 = offs[d], k1 = offs[d + 1];
  float mmax = -1e30f, den = 0.f, acc = 0.f;
  for (int kb = k0; kb < k1; kb += 64) {
    int nk = min(64, k1 - kb);
    int2 ce = make_int2(0, 0);
    if (lane < nk) ce = csr[kb + lane];
    for (int j = 0; j < nk; ++j) {
      int   s  = __shfl(ce.x, j);
      float ea = __int_as_float(__shfl(ce.y, j));
      float x = bf2f(xc2[(size_t)s * 128 + lane]);
      float m = x + fmaf(ea, ve, xr);
      m = fmaf(0.2f, fminf(m, 0.f), fmaxf(m, 0.f));
      float p = m * va;
#pragma unroll
      for (int off = 1; off <= 32; off <<= 1) p += __shfl_xor(p, off, 64);
      float hi = fmaxf(mmax, p);
      float lo = fminf(mmax, p);
      float t  = __expf(lo - hi);
      bool  up = p > mmax;
      float corr = up ? t : 1.0f;
      float w    = up ? 1.0f : t;
      den = fmaf(den, corr, w);
      acc = fmaf(acc, corr, w * x);
      mmax = hi;
    }
  }
  out[(size_t)d * OUT_DIM + lane] = acc / den + bias[lane];
}

extern "C" void kernel_launch(void* const* d_in, const int* in_sizes, int n_in,
                              void* d_out, int out_size, void* d_ws, size_t ws_size,
                              hipStream_t stream) {
  const float* x     = (const float*)d_in[0];
  const int*   ei    = (const int*)d_in[1];
  const float* eattr = (const float*)d_in[2];
  const float* W1l   = (const float*)d_in[3];
  const float* b1l   = (const float*)d_in[4];
  const float* W1r   = (const float*)d_in[5];
  const float* b1r   = (const float*)d_in[6];
  const float* W1e   = (const float*)d_in[7];
  const float* att1  = (const float*)d_in[8];
  const float* bias1 = (const float*)d_in[9];
  const float* W2l   = (const float*)d_in[10];
  const float* b2l   = (const float*)d_in[11];
  const float* W2r   = (const float*)d_in[12];
  const float* b2r   = (const float*)d_in[13];
  const float* W2e   = (const float*)d_in[14];
  const float* att2  = (const float*)d_in[15];
  const float* bias2 = (const float*)d_in[16];
  const int* src = ei;
  const int* dst = ei + E_EDGES;
  float* out = (float*)d_out;

  // workspace layout (bytes)
  char* w = (char*)d_ws;
  unsigned short* xb    = (unsigned short*)w;             w += (size_t)N_NODES * IN_DIM * 2;
  unsigned short* W1T   = (unsigned short*)w;             w += (size_t)IN_DIM * 512 * 2;
  unsigned short* W2T   = (unsigned short*)w;             w += (size_t)128 * HC1 * 2;
  unsigned short* xc1   = (unsigned short*)w;             w += (size_t)N_NODES * 512 * 2;
  unsigned short* h     = (unsigned short*)w;             w += (size_t)N_NODES * HC1 * 2;
  unsigned short* xc2   = (unsigned short*)w;             w += (size_t)N_NODES * 128 * 2;
  float* bcat1  = (float*)w;                              w += 512 * 4;
  float* bcat2  = (float*)w;                              w += 128 * 4;
  float* asum   = (float*)w;                              w += (size_t)N_NODES * 4;
  int* degi     = (int*)w;                                w += (size_t)N_NODES * 4;
  int* offs     = (int*)w;                                w += (size_t)(N_NODES + 1) * 4;
  int* cursor   = (int*)w;                                w += (size_t)N_NODES * 4;
  int2* csr     = (int2*)w;                               w += (size_t)EN_TOT * 8;

  hipMemsetAsync(degi, 0, sizeof(int) * N_NODES, stream);
  hipMemsetAsync(asum, 0, sizeof(float) * N_NODES, stream);

  const int T = 256;
  // CSR build (+ self-loop attr folded into fill_self)
  edge_stats_kernel<<<(E_EDGES + T - 1) / T, T, 0, stream>>>(dst, eattr, degi, asum);
  scan_kernel<<<1, 1024, 0, stream>>>(degi, offs);
  csr_fill_self_kernel<<<(N_NODES + T - 1) / T, T, 0, stream>>>(offs, degi, asum, cursor, csr);
  csr_fill_edges_kernel<<<(E_EDGES + T - 1) / T, T, 0, stream>>>(src, dst, eattr, offs, cursor, csr);

  // merged bf16 conversions / weight prep
  {
    int total = N_NODES * IN_DIM / 4 + 512 * 512 + 128 * 256;
    prep_kernel<<<(total + T - 1) / T, T, 0, stream>>>(x, xb, W1l, W1r, b1l, b1r, W1T, bcat1,
                                                       W2l, W2r, b2l, b2r, W2T, bcat2);
  }

  // layer 1: fused GEMM [N,512]@[512,512] -> xc1, then fused edge phase
  {
    dim3 grid((N_NODES + 127) / 128, 512 / 128);
    gemm_mfma_kernel<<<grid, T, 0, stream>>>(xb, W1T, bcat1, xc1, N_NODES, IN_DIM, 512);
  }
  fused1_kernel<<<(N_NODES + 3) / 4, T, 0, stream>>>(offs, csr, xc1, W1e, att1, bias1, h);

  // layer 2: fused GEMM [N,256]@[256,128] -> xc2, then fused edge phase
  {
    dim3 grid((N_NODES + 127) / 128, 128 / 128);
    gemm_mfma_kernel<<<grid, T, 0, stream>>>(h, W2T, bcat2, xc2, N_NODES, HC1, 128);
  }
  fused2_kernel<<<(N_NODES + 3) / 4, T, 0, stream>>>(offs, csr, xc2, W2e, att2, bias2, out);
}

// Round 6
// 217.839 us; speedup vs baseline: 7.6557x; 1.0608x over previous
//
#include <hip/hip_runtime.h>

#define N_NODES 20000
#define E_EDGES 320000
#define EN_TOT  (E_EDGES + N_NODES)   // edges + self loops = 340000
#define IN_DIM  512
#define H1      2
#define C1      128
#define HC1     256                    // H1*C1
#define OUT_DIM 64

typedef __attribute__((ext_vector_type(8))) short short8;
typedef __attribute__((ext_vector_type(4))) float f32x4;

__device__ __forceinline__ unsigned short f2bf(float f) {
  unsigned u = __float_as_uint(f);
  u += 0x7fffu + ((u >> 16) & 1u);    // RNE
  return (unsigned short)(u >> 16);
}
__device__ __forceinline__ float bf2f(unsigned short s) {
  return __uint_as_float(((unsigned)s) << 16);
}

// ---------- merged prep: x->bf16, W1 transpose+concat, W2 transpose+concat ----------
__global__ void prep_kernel(const float* __restrict__ x, unsigned short* __restrict__ xb,
                            const float* __restrict__ W1l, const float* __restrict__ W1r,
                            const float* __restrict__ b1l, const float* __restrict__ b1r,
                            unsigned short* __restrict__ W1T, float* __restrict__ bcat1,
                            const float* __restrict__ W2l, const float* __restrict__ W2r,
                            const float* __restrict__ b2l, const float* __restrict__ b2r,
                            unsigned short* __restrict__ W2T, float* __restrict__ bcat2) {
  int idx = blockIdx.x * blockDim.x + threadIdx.x;
  const int A  = N_NODES * IN_DIM / 4;
  const int B1 = 512 * 512;
  const int B2 = 128 * 256;
  if (idx < A) {
    float4 v = *reinterpret_cast<const float4*>(x + (size_t)idx * 4);
    ushort4 o;
    o.x = f2bf(v.x); o.y = f2bf(v.y); o.z = f2bf(v.z); o.w = f2bf(v.w);
    *reinterpret_cast<ushort4*>(xb + (size_t)idx * 4) = o;
  } else if (idx < A + B1) {
    int t = idx - A;                 // n*512 + k, n in [0,512)
    int n = t >> 9, k = t & 511;
    const float* W = (n < 256) ? W1l : W1r;
    int nn = n & 255;
    W1T[t] = f2bf(W[(size_t)k * 256 + nn]);
    if (k == 0) bcat1[n] = (n < 256) ? b1l[nn] : b1r[nn];
  } else if (idx < A + B1 + B2) {
    int t = idx - A - B1;            // n*256 + k, n in [0,128)
    int n = t >> 8, k = t & 255;
    const float* W = (n < 64) ? W2l : W2r;
    int nn = n & 63;
    W2T[t] = f2bf(W[(size_t)k * 64 + nn]);
    if (k == 0) bcat2[n] = (n < 64) ? b2l[nn] : b2r[nn];
  }
}

// ---------- bf16 MFMA GEMM: C[M,N] = A[M,K] @ BT[N,K]^T + bias, bf16 out ----------
__global__ __launch_bounds__(256) void gemm_mfma_kernel(
    const unsigned short* __restrict__ A,   // [M][K] bf16
    const unsigned short* __restrict__ BT,  // [N][K] bf16
    const float* __restrict__ bias,         // [N]
    unsigned short* __restrict__ C,         // [M][N] bf16
    int M, int K, int N) {
  constexpr int BM = 128, BK = 64;
  __shared__ short8 AsV[(BK / 8) * BM];   // 16KB, [kb][m] xor-swizzled
  __shared__ short8 BsV[(BK / 8) * BM];   // 16KB
  const int bm = blockIdx.x * BM;
  const int bn = blockIdx.y * BM;
  const int tid = threadIdx.x;
  const int lane = tid & 63;
  const int wave = tid >> 6;
  const int wr = wave >> 1, wc = wave & 1;   // 2x2 waves of 64x64
  const int lrow = lane & 15, lk = lane >> 4;

  f32x4 acc[4][4] = {};

  for (int k0 = 0; k0 < K; k0 += BK) {
#pragma unroll
    for (int i = 0; i < 4; ++i) {
      int c = tid + i * 256;
      int m = c >> 3, kb = c & 7;
      int gr = bm + m;
      short8 v = {};
      if (gr < M) v = *reinterpret_cast<const short8*>(A + (size_t)gr * K + k0 + kb * 8);
      AsV[((kb << 7) + m) ^ kb] = v;
    }
#pragma unroll
    for (int i = 0; i < 4; ++i) {
      int c = tid + i * 256;
      int n = c >> 3, kb = c & 7;
      short8 v = *reinterpret_cast<const short8*>(BT + (size_t)(bn + n) * K + k0 + kb * 8);
      BsV[((kb << 7) + n) ^ kb] = v;
    }
    __syncthreads();
#pragma unroll
    for (int ks = 0; ks < 2; ++ks) {
      int kb = ks * 4 + lk;
      short8 a[4], b[4];
#pragma unroll
      for (int mf = 0; mf < 4; ++mf)
        a[mf] = AsV[((kb << 7) + (wr * 64 + mf * 16 + lrow)) ^ kb];
#pragma unroll
      for (int nf = 0; nf < 4; ++nf)
        b[nf] = BsV[((kb << 7) + (wc * 64 + nf * 16 + lrow)) ^ kb];
#pragma unroll
      for (int mf = 0; mf < 4; ++mf)
#pragma unroll
        for (int nf = 0; nf < 4; ++nf)
          acc[mf][nf] = __builtin_amdgcn_mfma_f32_16x16x32_bf16(a[mf], b[nf], acc[mf][nf], 0, 0, 0);
    }
    __syncthreads();
  }
#pragma unroll
  for (int mf = 0; mf < 4; ++mf) {
#pragma unroll
    for (int r = 0; r < 4; ++r) {
      int row = bm + wr * 64 + mf * 16 + (lane >> 4) * 4 + r;
      if (row >= M) continue;
#pragma unroll
      for (int nf = 0; nf < 4; ++nf) {
        int col = bn + wc * 64 + nf * 16 + (lane & 15);
        C[(size_t)row * N + col] = f2bf(acc[mf][nf][r] + bias[col]);
      }
    }
  }
}

// ---------- edge stats: integer degree + attr sums ----------
__global__ void edge_stats_kernel(const int* __restrict__ dst, const float* __restrict__ eattr,
                                  int* __restrict__ degi, float* __restrict__ asum) {
  int e = blockIdx.x * blockDim.x + threadIdx.x;
  if (e >= E_EDGES) return;
  int d = dst[e];
  atomicAdd(&degi[d], 1);
  atomicAdd(&asum[d], eattr[e]);
}

// ---------- exclusive scan over row lengths (deg+1), single block ----------
__global__ void scan_kernel(const int* __restrict__ degi, int* __restrict__ offs) {
  __shared__ int psum[1024];
  const int T = 1024;
  int tid = threadIdx.x;
  const int per = (N_NODES + T - 1) / T;
  int base = tid * per;
  int s = 0;
  for (int i = 0; i < per; ++i) {
    int n = base + i;
    if (n < N_NODES) s += degi[n] + 1;
  }
  psum[tid] = s;
  __syncthreads();
  for (int off = 1; off < T; off <<= 1) {
    int v = (tid >= off) ? psum[tid - off] : 0;
    __syncthreads();
    psum[tid] += v;
    __syncthreads();
  }
  int run = (tid > 0) ? psum[tid - 1] : 0;
  for (int i = 0; i < per; ++i) {
    int n = base + i;
    if (n < N_NODES) {
      offs[n] = run;
      run += degi[n] + 1;
    }
  }
  if (tid == T - 1) offs[N_NODES] = run;
}

// ---------- CSR fill: interleaved (src, eattr-bits); self slot also computes loop attr ----------
__global__ void csr_fill_self_kernel(const int* __restrict__ offs, const int* __restrict__ degi,
                                     const float* __restrict__ asum, int* __restrict__ cursor,
                                     int2* __restrict__ csr) {
  int n = blockIdx.x * blockDim.x + threadIdx.x;
  if (n >= N_NODES) return;
  float la = asum[n] / fmaxf((float)degi[n], 1.0f);
  csr[offs[n]] = make_int2(n, __float_as_int(la));
  cursor[n] = 1;
}

__global__ void csr_fill_edges_kernel(const int* __restrict__ src, const int* __restrict__ dst,
                                      const float* __restrict__ eattr,
                                      const int* __restrict__ offs, int* __restrict__ cursor,
                                      int2* __restrict__ csr) {
  int e = blockIdx.x * blockDim.x + threadIdx.x;
  if (e >= E_EDGES) return;
  int d = dst[e];
  int p = offs[d] + atomicAdd(&cursor[d], 1);
  csr[p] = make_int2(src[e], __float_as_int(eattr[e]));
}

// ---------- fused layer 1: wave per node, 4-edge-batched online softmax ----------
// xc layout per row: [xl(256) | xr(256)]; lanes 0-31 = head0 (ch 0-127), 32-63 = head1
__global__ __launch_bounds__(256) void fused1_kernel(
    const int* __restrict__ offs, const int2* __restrict__ csr,
    const unsigned short* __restrict__ xc, const float* __restrict__ We,
    const float* __restrict__ att, const float* __restrict__ bias,
    unsigned short* __restrict__ hout) {
  int wid = threadIdx.x >> 6, lane = threadIdx.x & 63;
  int d = blockIdx.x * 4 + wid;
  if (d >= N_NODES) return;
  const int c4 = lane * 4;
  ushort4 ur = *reinterpret_cast<const ushort4*>(xc + (size_t)d * 512 + 256 + c4);
  float xr0 = bf2f(ur.x), xr1 = bf2f(ur.y), xr2 = bf2f(ur.z), xr3 = bf2f(ur.w);
  float4 ve = *reinterpret_cast<const float4*>(We + c4);
  float4 va = *reinterpret_cast<const float4*>(att + c4);
  int k0 = offs[d], k1 = offs[d + 1];
  float mmax = -1e30f, den = 0.f;
  float a0 = 0.f, a1 = 0.f, a2 = 0.f, a3 = 0.f;
  for (int kb = k0; kb < k1; kb += 64) {
    int nk = min(64, k1 - kb);
    int2 ce = make_int2(0, 0);
    if (lane < nk) ce = csr[kb + lane];
    for (int j = 0; j < nk; j += 4) {
      float p[4];
      float xv0[4], xv1[4], xv2[4], xv3[4];
#pragma unroll
      for (int i = 0; i < 4; ++i) {
        int jj = j + i;
        int   s  = __shfl(ce.x, jj);
        float ea = __int_as_float(__shfl(ce.y, jj));
        ushort4 ul = *reinterpret_cast<const ushort4*>(xc + (size_t)s * 512 + c4);
        float x0 = bf2f(ul.x), x1 = bf2f(ul.y), x2 = bf2f(ul.z), x3 = bf2f(ul.w);
        float m0 = x0 + fmaf(ea, ve.x, xr0);
        float m1 = x1 + fmaf(ea, ve.y, xr1);
        float m2 = x2 + fmaf(ea, ve.z, xr2);
        float m3 = x3 + fmaf(ea, ve.w, xr3);
        m0 = fmaf(0.2f, fminf(m0, 0.f), fmaxf(m0, 0.f));
        m1 = fmaf(0.2f, fminf(m1, 0.f), fmaxf(m1, 0.f));
        m2 = fmaf(0.2f, fminf(m2, 0.f), fmaxf(m2, 0.f));
        m3 = fmaf(0.2f, fminf(m3, 0.f), fmaxf(m3, 0.f));
        float pp = fmaf(m0, va.x, m1 * va.y) + fmaf(m2, va.z, m3 * va.w);
        p[i] = (jj < nk) ? pp : -1e30f;
        xv0[i] = x0; xv1[i] = x1; xv2[i] = x2; xv3[i] = x3;
      }
      // 4 interleaved butterflies (per 32-lane head group)
#pragma unroll
      for (int off = 1; off <= 16; off <<= 1) {
        p[0] += __shfl_xor(p[0], off, 64);
        p[1] += __shfl_xor(p[1], off, 64);
        p[2] += __shfl_xor(p[2], off, 64);
        p[3] += __shfl_xor(p[3], off, 64);
      }
      // batched online softmax update
      float nm = fmaxf(mmax, fmaxf(fmaxf(p[0], p[1]), fmaxf(p[2], p[3])));
      float corr = __expf(mmax - nm);
      float w0 = __expf(p[0] - nm);
      float w1 = __expf(p[1] - nm);
      float w2 = __expf(p[2] - nm);
      float w3 = __expf(p[3] - nm);
      mmax = nm;
      den = fmaf(den, corr, (w0 + w1) + (w2 + w3));
      a0 = fmaf(a0, corr, fmaf(w0, xv0[0], fmaf(w1, xv0[1], fmaf(w2, xv0[2], w3 * xv0[3]))));
      a1 = fmaf(a1, corr, fmaf(w0, xv1[0], fmaf(w1, xv1[1], fmaf(w2, xv1[2], w3 * xv1[3]))));
      a2 = fmaf(a2, corr, fmaf(w0, xv2[0], fmaf(w1, xv2[1], fmaf(w2, xv2[2], w3 * xv2[3]))));
      a3 = fmaf(a3, corr, fmaf(w0, xv3[0], fmaf(w1, xv3[1], fmaf(w2, xv3[2], w3 * xv3[3]))));
    }
  }
  float rden = 1.f / den;
  float4 b = *reinterpret_cast<const float4*>(bias + c4);
  float r0 = fmaf(a0, rden, b.x); r0 = r0 > 0.f ? r0 : expm1f(r0);
  float r1 = fmaf(a1, rden, b.y); r1 = r1 > 0.f ? r1 : expm1f(r1);
  float r2 = fmaf(a2, rden, b.z); r2 = r2 > 0.f ? r2 : expm1f(r2);
  float r3 = fmaf(a3, rden, b.w); r3 = r3 > 0.f ? r3 : expm1f(r3);
  ushort4 o;
  o.x = f2bf(r0); o.y = f2bf(r1); o.z = f2bf(r2); o.w = f2bf(r3);
  *reinterpret_cast<ushort4*>(hout + (size_t)d * HC1 + c4) = o;
}

// ---------- fused layer 2: wave per node, 64 channels, 1 head, 4-edge batched ----------
// xc2 layout per row: [xl(64) | xr(64)]
__global__ __launch_bounds__(256) void fused2_kernel(
    const int* __restrict__ offs, const int2* __restrict__ csr,
    const unsigned short* __restrict__ xc2, const float* __restrict__ We,
    const float* __restrict__ att, const float* __restrict__ bias,
    float* __restrict__ out) {
  int wid = threadIdx.x >> 6, lane = threadIdx.x & 63;
  int d = blockIdx.x * 4 + wid;
  if (d >= N_NODES) return;
  float xr = bf2f(xc2[(size_t)d * 128 + 64 + lane]);
  float ve = We[lane];
  float va = att[lane];
  int k0 = offs[d], k1 = offs[d + 1];
  float mmax = -1e30f, den = 0.f, acc = 0.f;
  for (int kb = k0; kb < k1; kb += 64) {
    int nk = min(64, k1 - kb);
    int2 ce = make_int2(0, 0);
    if (lane < nk) ce = csr[kb + lane];
    for (int j = 0; j < nk; j += 4) {
      float p[4], xv[4];
#pragma unroll
      for (int i = 0; i < 4; ++i) {
        int jj = j + i;
        int   s  = __shfl(ce.x, jj);
        float ea = __int_as_float(__shfl(ce.y, jj));
        float x = bf2f(xc2[(size_t)s * 128 + lane]);
        float m = x + fmaf(ea, ve, xr);
        m = fmaf(0.2f, fminf(m, 0.f), fmaxf(m, 0.f));
        float pp = m * va;
        p[i] = (jj < nk) ? pp : -1e30f;
        xv[i] = x;
      }
#pragma unroll
      for (int off = 1; off <= 32; off <<= 1) {
        p[0] += __shfl_xor(p[0], off, 64);
        p[1] += __shfl_xor(p[1], off, 64);
        p[2] += __shfl_xor(p[2], off, 64);
        p[3] += __shfl_xor(p[3], off, 64);
      }
      float nm = fmaxf(mmax, fmaxf(fmaxf(p[0], p[1]), fmaxf(p[2], p[3])));
      float corr = __expf(mmax - nm);
      float w0 = __expf(p[0] - nm);
      float w1 = __expf(p[1] - nm);
      float w2 = __expf(p[2] - nm);
      float w3 = __expf(p[3] - nm);
      mmax = nm;
      den = fmaf(den, corr, (w0 + w1) + (w2 + w3));
      acc = fmaf(acc, corr, fmaf(w0, xv[0], fmaf(w1, xv[1], fmaf(w2, xv[2], w3 * xv[3]))));
    }
  }
  out[(size_t)d * OUT_DIM + lane] = acc / den + bias[lane];
}

extern "C" void kernel_launch(void* const* d_in, const int* in_sizes, int n_in,
                              void* d_out, int out_size, void* d_ws, size_t ws_size,
                              hipStream_t stream) {
  const float* x     = (const float*)d_in[0];
  const int*   ei    = (const int*)d_in[1];
  const float* eattr = (const float*)d_in[2];
  const float* W1l   = (const float*)d_in[3];
  const float* b1l   = (const float*)d_in[4];
  const float* W1r   = (const float*)d_in[5];
  const float* b1r   = (const float*)d_in[6];
  const float* W1e   = (const float*)d_in[7];
  const float* att1  = (const float*)d_in[8];
  const float* bias1 = (const float*)d_in[9];
  const float* W2l   = (const float*)d_in[10];
  const float* b2l   = (const float*)d_in[11];
  const float* W2r   = (const float*)d_in[12];
  const float* b2r   = (const float*)d_in[13];
  const float* W2e   = (const float*)d_in[14];
  const float* att2  = (const float*)d_in[15];
  const float* bias2 = (const float*)d_in[16];
  const int* src = ei;
  const int* dst = ei + E_EDGES;
  float* out = (float*)d_out;

  // workspace layout (bytes)
  char* w = (char*)d_ws;
  unsigned short* xb    = (unsigned short*)w;             w += (size_t)N_NODES * IN_DIM * 2;
  unsigned short* W1T   = (unsigned short*)w;             w += (size_t)IN_DIM * 512 * 2;
  unsigned short* W2T   = (unsigned short*)w;             w += (size_t)128 * HC1 * 2;
  unsigned short* xc1   = (unsigned short*)w;             w += (size_t)N_NODES * 512 * 2;
  unsigned short* h     = (unsigned short*)w;             w += (size_t)N_NODES * HC1 * 2;
  unsigned short* xc2   = (unsigned short*)w;             w += (size_t)N_NODES * 128 * 2;
  float* bcat1  = (float*)w;                              w += 512 * 4;
  float* bcat2  = (float*)w;                              w += 128 * 4;
  float* asum   = (float*)w;                              w += (size_t)N_NODES * 4;
  int* degi     = (int*)w;                                w += (size_t)N_NODES * 4;
  int* offs     = (int*)w;                                w += (size_t)(N_NODES + 1) * 4;
  int* cursor   = (int*)w;                                w += (size_t)N_NODES * 4;
  int2* csr     = (int2*)w;                               w += (size_t)EN_TOT * 8;

  hipMemsetAsync(degi, 0, sizeof(int) * N_NODES, stream);
  hipMemsetAsync(asum, 0, sizeof(float) * N_NODES, stream);

  const int T = 256;
  // CSR build (+ self-loop attr folded into fill_self)
  edge_stats_kernel<<<(E_EDGES + T - 1) / T, T, 0, stream>>>(dst, eattr, degi, asum);
  scan_kernel<<<1, 1024, 0, stream>>>(degi, offs);
  csr_fill_self_kernel<<<(N_NODES + T - 1) / T, T, 0, stream>>>(offs, degi, asum, cursor, csr);
  csr_fill_edges_kernel<<<(E_EDGES + T - 1) / T, T, 0, stream>>>(src, dst, eattr, offs, cursor, csr);

  // merged bf16 conversions / weight prep
  {
    int total = N_NODES * IN_DIM / 4 + 512 * 512 + 128 * 256;
    prep_kernel<<<(total + T - 1) / T, T, 0, stream>>>(x, xb, W1l, W1r, b1l, b1r, W1T, bcat1,
                                                       W2l, W2r, b2l, b2r, W2T, bcat2);
  }

  // layer 1: fused GEMM [N,512]@[512,512] -> xc1, then fused edge phase
  {
    dim3 grid((N_NODES + 127) / 128, 512 / 128);
    gemm_mfma_kernel<<<grid, T, 0, stream>>>(xb, W1T, bcat1, xc1, N_NODES, IN_DIM, 512);
  }
  fused1_kernel<<<(N_NODES + 3) / 4, T, 0, stream>>>(offs, csr, xc1, W1e, att1, bias1, h);

  // layer 2: fused GEMM [N,256]@[256,128] -> xc2, then fused edge phase
  {
    dim3 grid((N_NODES + 127) / 128, 128 / 128);
    gemm_mfma_kernel<<<grid, T, 0, stream>>>(h, W2T, bcat2, xc2, N_NODES, HC1, 128);
  }
  fused2_kernel<<<(N_NODES + 3) / 4, T, 0, stream>>>(offs, csr, xc2, W2e, att2, bias2, out);
}